// Round 10
// baseline (357.713 us; speedup 1.0000x reference)
//
#include <hip/hip_runtime.h>

// GraphSAGE 3-layer forward, MI355X. Round 19 (= R17 + L2-resident gather):
//   R18 widening regressed (occupancy loss > instr savings) - reverted.
//   Root cause of gather plateau (R17 counters): H = 12.8MB > 4MB per-XCD L2
//   -> ~70% of E x 256B row traffic refills L3 at ~1.75 TB/s. Fix the LAYOUT:
//   - H stored column-blocked Hcb[4][N][32] (slice = 3.2MB < 4MB L2).
//   - dedicated gatherM kernel, slice = blockIdx & 3: round-robin block->XCD
//     gives slice s XCDs {s,s+4}, each caching only its slice -> all-L2-hit
//     gather at 64B granules. M materializes to Mcb (overlays dead T).
//   - gemm kernels lose the gather (A-frags stream from Mcb/Hcb coalesced).
//   - Y2 col-blocked [2][N][32] for the final gather; out/F unchanged.
//   Bounded downside: if XCD affinity fails, behavior = today's + M trip.

constexpr int N = 50000;
constexpr int E = 800000;
constexpr int NBUCK = (N + 255) / 256;    // 196 dst-buckets
constexpr int CE = 4096;                  // edges per scatter chunk
constexpr int NEB = (E + CE - 1) / CE;    // 196
constexpr int SLOT = 6208;                // 4096 exp + sigma + 8-align pad
constexpr int GNB = (N + 63) / 64;        // 782 gather nodeblocks (64 nodes)
static_assert(N <= 65536, "u16 packing");
static_assert(N % 16 == 0, "16-row gemm blocks need no bounds checks");

typedef _Float16 f16x8 __attribute__((ext_vector_type(8)));
typedef _Float16 f16x2 __attribute__((ext_vector_type(2)));
typedef float f32x4 __attribute__((ext_vector_type(4)));
typedef unsigned short u16x8 __attribute__((ext_vector_type(8)));

constexpr int CONVB = (N * 128 / 8 + 255) / 256;   // 3125 convert blocks
constexpr int MASKB = (N * 128) / (8 * 256);       // 3125 blocks per mask

// ---------------- merged setup + scatter + masks ---------------------------
// Wf[((ct*KB+kb)*64+lane)*8+j] = Wcat[ct*16+(lane&15)][kb*32+(lane>>4)*8+j]
__device__ inline void wfrag_build(int idx, int KB, const float* wl,
                                   const float* wr, _Float16* wf) {
  int j = idx & 7;
  int lane = (idx >> 3) & 63;
  int kb = (idx >> 9) % KB;
  int ct = (idx >> 9) / KB;
  int c = ct * 16 + (lane & 15);
  int k = kb * 32 + (lane >> 4) * 8 + j;
  float v = (k < 128) ? wl[c * 128 + k] : wr[c * 128 + (k - 128)];
  wf[idx] = (_Float16)v;
}

__global__ __launch_bounds__(256) void setup_scatter_kernel(
    const int* __restrict__ src, const int* __restrict__ dst,
    int* __restrict__ bcur, unsigned* __restrict__ T,
    const float* __restrict__ x,
    const float* __restrict__ u1, const float* __restrict__ u2,
    const float* __restrict__ wl0, const float* __restrict__ wr0,
    const float* __restrict__ wl1, const float* __restrict__ wr1,
    const float* __restrict__ wl2, const float* __restrict__ wr2,
    _Float16* __restrict__ HAcb, _Float16* __restrict__ wf0,
    _Float16* __restrict__ wf1, _Float16* __restrict__ wfZ,
    unsigned* __restrict__ mk1, unsigned* __restrict__ mk2) {
  __shared__ unsigned sorted[CE];
  __shared__ int hist[256], scan[256], excl[256], lcur[256], gbase[256];
  const int b = blockIdx.x;
  const int t = threadIdx.x;
  if (b < NEB) {                          // ---- scatter branch ----
    const int e0 = b * CE;
    const int nval = min(CE, E - e0);
    hist[t] = 0;
    __syncthreads();
    for (int i = t; i < nval; i += 256) atomicAdd(&hist[dst[e0 + i] >> 8], 1);
    __syncthreads();
    const int h = hist[t];
    scan[t] = h;
    __syncthreads();
    for (int off = 1; off < 256; off <<= 1) {
      int u = (t >= off) ? scan[t - off] : 0;
      __syncthreads();
      scan[t] += u;
      __syncthreads();
    }
    excl[t] = scan[t] - h;
    lcur[t] = scan[t] - h;
    gbase[t] = (t < NBUCK && h > 0) ? (t * SLOT + atomicAdd(&bcur[t], h)) : 0;
    __syncthreads();
    for (int i = t; i < nval; i += 256) {
      int e = e0 + i;
      int d = dst[e];
      int p = atomicAdd(&lcur[d >> 8], 1);
      sorted[p] = ((unsigned)d << 16) | (unsigned)src[e];
    }
    __syncthreads();
    for (int i = t; i < nval; i += 256) {
      unsigned pk = sorted[i];
      int bb = pk >> 24;                  // == dst>>8
      T[gbase[bb] + (i - excl[bb])] = pk;
    }
    return;
  }
  const int b2 = b - NEB;
  if (b2 < CONVB) {                       // ---- convert: x -> HAcb ----
    int i = b2 * 256 + t;                 // one thread per 8 elems (octet)
    if (i < N * 128 / 8) {
      int n = i >> 4, o = i & 15;         // octet o covers cols o*8..o*8+7
      float4 a = ((const float4*)x)[i * 2];
      float4 c = ((const float4*)x)[i * 2 + 1];
      f16x8 v;
      v[0] = (_Float16)a.x; v[1] = (_Float16)a.y; v[2] = (_Float16)a.z; v[3] = (_Float16)a.w;
      v[4] = (_Float16)c.x; v[5] = (_Float16)c.y; v[6] = (_Float16)c.z; v[7] = (_Float16)c.w;
      *(f16x8*)(HAcb + ((size_t)(o >> 2) * N + n) * 32 + (o & 3) * 8) = v;
    }
  } else if (b2 < CONVB + 128) {          // wf0: [wl0|wr0], K=256
    wfrag_build((b2 - CONVB) * 256 + t, 8, wl0, wr0, wf0);
  } else if (b2 < CONVB + 256) {          // wf1: [wl1|wr1]
    wfrag_build((b2 - CONVB - 128) * 256 + t, 8, wl1, wr1, wf1);
  } else if (b2 < CONVB + 320) {          // wfZ: 64 blocks
    int idx = (b2 - CONVB - 256) * 256 + t;
    int j = idx & 7;
    int lane = (idx >> 3) & 63;
    int kb = (idx >> 9) & 3;
    int ct = idx >> 11;                   // 0..7
    int c = ct * 16 + (lane & 15);
    int k = kb * 32 + (lane >> 4) * 8 + j;
    float v = (c < 64) ? wl2[c * 128 + k] : wr2[(c - 64) * 128 + k];
    wfZ[idx] = (_Float16)v;
  } else {                                // ---- mask branch ----
    int mb = b2 - (CONVB + 320);
    const float* Us = (mb < MASKB) ? u1 : u2;
    unsigned* MKs = (mb < MASKB) ? mk1 : mk2;
    int bb = (mb < MASKB) ? mb : (mb - MASKB);
#pragma unroll
    for (int k = 0; k < 8; ++k) {
      int i = (bb * 8 + k) * 256 + t;
      unsigned long long m = __ballot(Us[i] >= 0.3f);
      int lt = t & 63;
      if (lt == 0) MKs[i >> 5] = (unsigned)m;
      else if (lt == 32) MKs[i >> 5] = (unsigned)(m >> 32);
    }
  }
}

// Phase B: one block per bucket; offsets/degrees with 8-ALIGNED segments.
__global__ __launch_bounds__(256) void bucket_place_kernel(
    const unsigned* __restrict__ T, const int* __restrict__ bcur,
    int* __restrict__ offs, int* __restrict__ deg,
    unsigned short* __restrict__ elist) {
  __shared__ int dcnt[256], s[256], ncur[256];
  const int t = threadIdx.x;
  const int b = blockIdx.x;
  const int lo = b * SLOT;
  const int hi = lo + bcur[b];
  dcnt[t] = 0;
  __syncthreads();
  for (int i = lo + t; i < hi; i += 256) atomicAdd(&dcnt[(T[i] >> 16) & 255], 1);
  __syncthreads();
  const int v = dcnt[t];
  const int pv = (v + 7) & ~7;            // 8-aligned segment length
  s[t] = pv;
  __syncthreads();
  for (int off = 1; off < 256; off <<= 1) {
    int u = (t >= off) ? s[t - off] : 0;
    __syncthreads();
    s[t] += u;
    __syncthreads();
  }
  const int base = lo + s[t] - pv;
  const int node = b * 256 + t;
  if (node < N) { offs[node] = base; deg[node] = v; }
  ncur[t] = base;
  __syncthreads();
  for (int i = lo + t; i < hi; i += 256) {
    unsigned pk = T[i];
    int pos = atomicAdd(&ncur[(pk >> 16) & 255], 1);
    elist[pos] = (unsigned short)(pk & 0xffffu);
  }
}

// ---------------- gatherM: col-sliced L2-resident gather-mean --------------
// slice = bid&3 (XCD affinity: XCDs {s,s+4} cache slice s = 3.2MB). Half-wave
// per node-step: 16 lanes x f16x2 (64B/edge-slice), 2 edge slots; 8 nodes.
__global__ __launch_bounds__(256, 8) void gatherM_kernel(
    const _Float16* __restrict__ Hcb, const int* __restrict__ offs,
    const int* __restrict__ deg, const unsigned short* __restrict__ elist,
    _Float16* __restrict__ Mcb) {
  const int s = blockIdx.x & 3;
  const int nb = blockIdx.x >> 2;
  const _Float16* Hs = Hcb + (size_t)s * N * 32;
  _Float16* Ms = Mcb + (size_t)s * N * 32;
  const int t = threadIdx.x;
  const int hw = t >> 5;                  // 0..7
  const int ll = t & 31;
  const int g = ll >> 4;                  // edge slot 0/1
  const int cl = ll & 15;                 // col pair: cols 2*cl, 2*cl+1
#pragma unroll 1
  for (int i = 0; i < 8; ++i) {
    int node = nb * 64 + hw * 8 + i;
    if (node >= N) break;
    const int e0 = offs[node];            // e0 % 8 == 0
    const int d = deg[node];
    const int e1 = e0 + d;
    float a0 = 0.f, a1 = 0.f;
    int e = e0;
    for (; e + 8 <= e1; e += 8) {
      u16x8 qv = *(const u16x8*)(elist + e);   // uniform across half-wave
      f16x2 v[4];
#pragma unroll
      for (int u = 0; u < 4; ++u)
        v[u] = *(const f16x2*)(Hs + (size_t)qv[2 * u + g] * 32 + cl * 2);
#pragma unroll
      for (int u = 0; u < 4; ++u) { a0 += (float)v[u][0]; a1 += (float)v[u][1]; }
    }
    for (; e + 2 <= e1; e += 2) {
      f16x2 v = *(const f16x2*)(Hs + (size_t)elist[e + g] * 32 + cl * 2);
      a0 += (float)v[0]; a1 += (float)v[1];
    }
    if (e < e1 && g == 0) {
      f16x2 v = *(const f16x2*)(Hs + (size_t)elist[e] * 32 + cl * 2);
      a0 += (float)v[0]; a1 += (float)v[1];
    }
    a0 += __shfl_xor(a0, 16);
    a1 += __shfl_xor(a1, 16);
    if (g == 0) {
      float inv = 1.0f / (float)max(d, 1);
      f16x2 o;
      o[0] = (_Float16)(a0 * inv); o[1] = (_Float16)(a1 * inv);
      *(f16x2*)(Ms + (size_t)node * 32 + cl * 2) = o;
    }
  }
}

// ---------------- gemm128: A=[Mcb|Hcb] (K=256) -> relu/dropout -> outcb ----
__global__ __launch_bounds__(256, 8) void gemm128_kernel(
    const _Float16* __restrict__ Hcb, const _Float16* __restrict__ Mcb,
    const _Float16* __restrict__ Wf, const float* __restrict__ bias,
    const unsigned* __restrict__ MK, _Float16* __restrict__ outcb) {
  __shared__ __align__(16) _Float16 Af[8][64][8];      // 8 KB
  const int t = threadIdx.x;
  const int rowbase = blockIdx.x * 16;
  {
    int r = t >> 4, o = t & 15;
    size_t base = ((size_t)(o >> 2) * N + rowbase + r) * 32 + (o & 3) * 8;
    *(f16x8*)&Af[4 + (o >> 2)][(o & 3) * 16 + r][0] = *(const f16x8*)(Hcb + base);
    *(f16x8*)&Af[o >> 2][(o & 3) * 16 + r][0] = *(const f16x8*)(Mcb + base);
  }
  __syncthreads();

  const int lane = t & 63;
  const int w = t >> 6;
  const int n16 = lane & 15;
  const int qq = lane >> 4;
  const int colbase = w * 32;

  f32x4 acc[2];
  acc[0] = (f32x4){0.f, 0.f, 0.f, 0.f};
  acc[1] = (f32x4){0.f, 0.f, 0.f, 0.f};
#pragma unroll
  for (int kb = 0; kb < 8; ++kb) {
    f16x8 a = *(const f16x8*)&Af[kb][lane][0];
#pragma unroll
    for (int ct = 0; ct < 2; ++ct) {
      const int ctg = w * 2 + ct;
      f16x8 b = *(const f16x8*)(Wf + ((size_t)(ctg * 8 + kb) * 64 + lane) * 8);
      acc[ct] = __builtin_amdgcn_mfma_f32_16x16x32_f16(a, b, acc[ct], 0, 0, 0);
    }
  }
  // C/D: col = lane&15, row = (lane>>4)*4 + reg. Store col-blocked.
#pragma unroll
  for (int r = 0; r < 4; ++r) {
    int row = rowbase + qq * 4 + r;
    unsigned mw = MK[(size_t)row * 4 + w];
#pragma unroll
    for (int ct = 0; ct < 2; ++ct) {
      const int col = colbase + ct * 16 + n16;
      float v = fmaxf(acc[ct][r] + bias[col], 0.f);
      v = ((mw >> (ct * 16 + n16)) & 1u) ? v * (1.0f / 0.7f) : 0.0f;
      outcb[((size_t)(col >> 5) * N + row) * 32 + (col & 31)] = (_Float16)v;
    }
  }
}

// ---------------- gemmZ: layer-1 GEMM + layer-2 GEMM (h1 in LDS only) ------
__global__ __launch_bounds__(256, 8) void gemmZ_kernel(
    const _Float16* __restrict__ Hcb, const _Float16* __restrict__ Mcb,
    const _Float16* __restrict__ Wf, const float* __restrict__ bias,
    const unsigned* __restrict__ MK, const _Float16* __restrict__ WfZ,
    const float* __restrict__ bl2, _Float16* __restrict__ Y2cb,
    float* __restrict__ F) {
  __shared__ __align__(16) _Float16 Af[8][64][8];      // 8 KB
  __shared__ __align__(16) _Float16 Zf[16][136];       // 4.25 KB
  const int t = threadIdx.x;
  const int rowbase = blockIdx.x * 16;
  {
    int r = t >> 4, o = t & 15;
    size_t base = ((size_t)(o >> 2) * N + rowbase + r) * 32 + (o & 3) * 8;
    *(f16x8*)&Af[4 + (o >> 2)][(o & 3) * 16 + r][0] = *(const f16x8*)(Hcb + base);
    *(f16x8*)&Af[o >> 2][(o & 3) * 16 + r][0] = *(const f16x8*)(Mcb + base);
  }
  __syncthreads();

  const int lane = t & 63;
  const int w = t >> 6;
  const int n16 = lane & 15;
  const int qq = lane >> 4;
  const int colbase = w * 32;

  f32x4 acc[2];
  acc[0] = (f32x4){0.f, 0.f, 0.f, 0.f};
  acc[1] = (f32x4){0.f, 0.f, 0.f, 0.f};
#pragma unroll
  for (int kb = 0; kb < 8; ++kb) {
    f16x8 a = *(const f16x8*)&Af[kb][lane][0];
#pragma unroll
    for (int ct = 0; ct < 2; ++ct) {
      const int ctg = w * 2 + ct;
      f16x8 b = *(const f16x8*)(Wf + ((size_t)(ctg * 8 + kb) * 64 + lane) * 8);
      acc[ct] = __builtin_amdgcn_mfma_f32_16x16x32_f16(a, b, acc[ct], 0, 0, 0);
    }
  }
  // h1 = dropout(relu(acc+bias)) -> Zf
#pragma unroll
  for (int r = 0; r < 4; ++r) {
    int row = qq * 4 + r;                 // local 0..15
    unsigned mw = MK[(size_t)(rowbase + row) * 4 + w];
#pragma unroll
    for (int ct = 0; ct < 2; ++ct) {
      const int col = colbase + ct * 16 + n16;
      float v = fmaxf(acc[ct][r] + bias[col], 0.f);
      v = ((mw >> (ct * 16 + n16)) & 1u) ? v * (1.0f / 0.7f) : 0.0f;
      Zf[row][col] = (_Float16)v;
    }
  }
  __syncthreads();

  // layer-2 GEMM: A = Zf rows (K=128), B = WfZ
  f32x4 az[2];
  az[0] = (f32x4){0.f, 0.f, 0.f, 0.f};
  az[1] = (f32x4){0.f, 0.f, 0.f, 0.f};
#pragma unroll
  for (int kb = 0; kb < 4; ++kb) {
    f16x8 a = *(const f16x8*)&Zf[n16][kb * 32 + qq * 8];
#pragma unroll
    for (int ct = 0; ct < 2; ++ct) {
      const int ctg = w * 2 + ct;
      f16x8 b = *(const f16x8*)(WfZ + ((size_t)(ctg * 4 + kb) * 64 + lane) * 8);
      az[ct] = __builtin_amdgcn_mfma_f32_16x16x32_f16(a, b, az[ct], 0, 0, 0);
    }
  }
#pragma unroll
  for (int ct = 0; ct < 2; ++ct) {
    const int col = colbase + ct * 16 + n16;   // 0..127
#pragma unroll
    for (int r = 0; r < 4; ++r) {
      int row = rowbase + qq * 4 + r;
      float v = az[ct][r];
      if (col < 64)
        Y2cb[((size_t)(col >> 5) * N + row) * 32 + (col & 31)] = (_Float16)v;
      else
        F[(size_t)row * 64 + (col - 64)] = v + bl2[col - 64];
    }
  }
}

// ---------------- gatherY: col-sliced final gather + add -------------------
// slice = bid&1 (XCD affinity: evens/odds cache 3.2MB slice). out = F + mean.
__global__ __launch_bounds__(256, 8) void gatherY_kernel(
    const _Float16* __restrict__ Y2cb, const float* __restrict__ F,
    const int* __restrict__ offs, const int* __restrict__ deg,
    const unsigned short* __restrict__ elist, float* __restrict__ out) {
  const int s = blockIdx.x & 1;
  const int nb = blockIdx.x >> 1;
  const _Float16* Ys = Y2cb + (size_t)s * N * 32;
  const int t = threadIdx.x;
  const int hw = t >> 5;
  const int ll = t & 31;
  const int g = ll >> 4;
  const int cl = ll & 15;
#pragma unroll 1
  for (int i = 0; i < 8; ++i) {
    int node = nb * 64 + hw * 8 + i;
    if (node >= N) break;
    const int e0 = offs[node];
    const int d = deg[node];
    const int e1 = e0 + d;
    float a0 = 0.f, a1 = 0.f;
    int e = e0;
    for (; e + 8 <= e1; e += 8) {
      u16x8 qv = *(const u16x8*)(elist + e);
      f16x2 v[4];
#pragma unroll
      for (int u = 0; u < 4; ++u)
        v[u] = *(const f16x2*)(Ys + (size_t)qv[2 * u + g] * 32 + cl * 2);
#pragma unroll
      for (int u = 0; u < 4; ++u) { a0 += (float)v[u][0]; a1 += (float)v[u][1]; }
    }
    for (; e + 2 <= e1; e += 2) {
      f16x2 v = *(const f16x2*)(Ys + (size_t)elist[e + g] * 32 + cl * 2);
      a0 += (float)v[0]; a1 += (float)v[1];
    }
    if (e < e1 && g == 0) {
      f16x2 v = *(const f16x2*)(Ys + (size_t)elist[e] * 32 + cl * 2);
      a0 += (float)v[0]; a1 += (float)v[1];
    }
    a0 += __shfl_xor(a0, 16);
    a1 += __shfl_xor(a1, 16);
    if (g == 0) {
      float inv = 1.0f / (float)max(d, 1);
      const float* fp = F + (size_t)node * 64 + s * 32 + cl * 2;
      float2 f = *(const float2*)fp;
      float2 o;
      o.x = f.x + a0 * inv;
      o.y = f.y + a1 * inv;
      *(float2*)(out + (size_t)node * 64 + s * 32 + cl * 2) = o;
    }
  }
}

extern "C" void kernel_launch(void* const* d_in, const int* in_sizes, int n_in,
                              void* d_out, int out_size, void* d_ws, size_t ws_size,
                              hipStream_t stream) {
  const float* x   = (const float*)d_in[0];
  const float* u1  = (const float*)d_in[1];
  const float* u2  = (const float*)d_in[2];
  const float* wl0 = (const float*)d_in[3];
  const float* bl0 = (const float*)d_in[4];
  const float* wr0 = (const float*)d_in[5];
  const float* wl1 = (const float*)d_in[6];
  const float* bl1 = (const float*)d_in[7];
  const float* wr1 = (const float*)d_in[8];
  const float* wl2 = (const float*)d_in[9];
  const float* bl2 = (const float*)d_in[10];
  const float* wr2 = (const float*)d_in[11];
  const int* edge  = (const int*)d_in[12];
  const int* src = edge;
  const int* dst = edge + E;

  // workspace layout (col-blocked H/M/Y2)
  _Float16* HAcb = (_Float16*)d_ws;                // [4][N][32] = N*128 f16
  _Float16* HBcb = HAcb + (size_t)N * 128;         // [4][N][32]
  _Float16* Y2cb = HBcb + (size_t)N * 128;         // [2][N][32] = N*64 f16
  float* F      = (float*)(Y2cb + (size_t)N * 64); // N x 64 f32
  int* offs     = (int*)(F + (size_t)N * 64);      // N
  int* deg      = offs + N;                        // N
  unsigned short* elist = (unsigned short*)(deg + N);  // NBUCK*SLOT u16
  uintptr_t pu = (uintptr_t)(elist + NBUCK * SLOT);
  pu = (pu + 15) & ~(uintptr_t)15;
  // union region: T (scatter staging, dead after place) / Mcb (after place)
  unsigned* T   = (unsigned*)pu;                   // NBUCK*SLOT u32 (4.9MB)
  _Float16* Mcb = (_Float16*)pu;                   // [4][N][32] (12.8MB)
  uintptr_t p2 = pu + (size_t)N * 128 * sizeof(_Float16);
  int* bcur     = (int*)p2;                        // NBUCK (counts)
  uintptr_t p = (uintptr_t)(bcur + NBUCK);
  p = (p + 15) & ~(uintptr_t)15;
  _Float16* wf0 = (_Float16*)p;                    // 8*8*512
  _Float16* wf1 = wf0 + 8 * 8 * 512;
  _Float16* wfZ = wf1 + 8 * 8 * 512;               // 8*4*512
  unsigned* mk1 = (unsigned*)(wfZ + 8 * 4 * 512);  // N*4 u32
  unsigned* mk2 = mk1 + (size_t)N * 4;             // N*4 u32

  // 0) bcur counts = 0
  hipMemsetAsync(bcur, 0, NBUCK * sizeof(int), stream);
  // 1) merged setup + scatter + masks
  setup_scatter_kernel<<<NEB + CONVB + 320 + 2 * MASKB, 256, 0, stream>>>(
      src, dst, bcur, T, x, u1, u2, wl0, wr0, wl1, wr1, wl2, wr2,
      HAcb, wf0, wf1, wfZ, mk1, mk2);
  // 2) place
  bucket_place_kernel<<<NBUCK, 256, 0, stream>>>(T, bcur, offs, deg, elist);

  // ---- Layer 0 ----
  gatherM_kernel<<<4 * GNB, 256, 0, stream>>>(HAcb, offs, deg, elist, Mcb);
  gemm128_kernel<<<N / 16, 256, 0, stream>>>(HAcb, Mcb, wf0, bl0, mk1, HBcb);
  // ---- Layer 1 (+ layer-2 GEMM fused) ----
  gatherM_kernel<<<4 * GNB, 256, 0, stream>>>(HBcb, offs, deg, elist, Mcb);
  gemmZ_kernel<<<N / 16, 256, 0, stream>>>(HBcb, Mcb, wf1, bl1, mk2, wfZ, bl2,
                                           Y2cb, F);
  // ---- Layer 2 gather + add ----
  gatherY_kernel<<<2 * GNB, 256, 0, stream>>>(Y2cb, F, offs, deg, elist,
                                              (float*)d_out);
}

// Round 11
// 334.436 us; speedup vs baseline: 1.0696x; 1.0696x over previous
//
#include <hip/hip_runtime.h>

// GraphSAGE 3-layer forward, MI355X. Round 20 (= R19 + gather inner-loop fix):
//   R19 post-mortem: L2-residency WORKED (gatherM FETCH 24.5MB vs 84MB) but
//   gatherM ran 65us at 54% VALU / 650 GB/s: instruction-bound. Causes:
//   f16x2 (4B/lane) loads = 2x VMEM per byte, and qv[runtime g] register-
//   vector extraction chains. Fix (structure unchanged):
//   - 8 lanes x f16x4 per edge-slice; 4 edge slots/half-wave; 16-edge batch
//     -> 4 row loads + 4 idx loads in flight; same bytes/instr as R17.
//   - per-lane scalar u16 index loads (no vector extract).
//   - reduce across slots: shfl_xor 8,16; g==0 writes f16x4/float4.

constexpr int N = 50000;
constexpr int E = 800000;
constexpr int NBUCK = (N + 255) / 256;    // 196 dst-buckets
constexpr int CE = 4096;                  // edges per scatter chunk
constexpr int NEB = (E + CE - 1) / CE;    // 196
constexpr int SLOT = 6208;                // 4096 exp + sigma + 8-align pad
constexpr int GNB = (N + 63) / 64;        // 782 gather nodeblocks (64 nodes)
static_assert(N <= 65536, "u16 packing");
static_assert(N % 16 == 0, "16-row gemm blocks need no bounds checks");

typedef _Float16 f16x8 __attribute__((ext_vector_type(8)));
typedef _Float16 f16x4 __attribute__((ext_vector_type(4)));
typedef _Float16 f16x2 __attribute__((ext_vector_type(2)));
typedef float f32x4 __attribute__((ext_vector_type(4)));

constexpr int CONVB = (N * 128 / 8 + 255) / 256;   // 3125 convert blocks
constexpr int MASKB = (N * 128) / (8 * 256);       // 3125 blocks per mask

// ---------------- merged setup + scatter + masks ---------------------------
// Wf[((ct*KB+kb)*64+lane)*8+j] = Wcat[ct*16+(lane&15)][kb*32+(lane>>4)*8+j]
__device__ inline void wfrag_build(int idx, int KB, const float* wl,
                                   const float* wr, _Float16* wf) {
  int j = idx & 7;
  int lane = (idx >> 3) & 63;
  int kb = (idx >> 9) % KB;
  int ct = (idx >> 9) / KB;
  int c = ct * 16 + (lane & 15);
  int k = kb * 32 + (lane >> 4) * 8 + j;
  float v = (k < 128) ? wl[c * 128 + k] : wr[c * 128 + (k - 128)];
  wf[idx] = (_Float16)v;
}

__global__ __launch_bounds__(256) void setup_scatter_kernel(
    const int* __restrict__ src, const int* __restrict__ dst,
    int* __restrict__ bcur, unsigned* __restrict__ T,
    const float* __restrict__ x,
    const float* __restrict__ u1, const float* __restrict__ u2,
    const float* __restrict__ wl0, const float* __restrict__ wr0,
    const float* __restrict__ wl1, const float* __restrict__ wr1,
    const float* __restrict__ wl2, const float* __restrict__ wr2,
    _Float16* __restrict__ HAcb, _Float16* __restrict__ wf0,
    _Float16* __restrict__ wf1, _Float16* __restrict__ wfZ,
    unsigned* __restrict__ mk1, unsigned* __restrict__ mk2) {
  __shared__ unsigned sorted[CE];
  __shared__ int hist[256], scan[256], excl[256], lcur[256], gbase[256];
  const int b = blockIdx.x;
  const int t = threadIdx.x;
  if (b < NEB) {                          // ---- scatter branch ----
    const int e0 = b * CE;
    const int nval = min(CE, E - e0);
    hist[t] = 0;
    __syncthreads();
    for (int i = t; i < nval; i += 256) atomicAdd(&hist[dst[e0 + i] >> 8], 1);
    __syncthreads();
    const int h = hist[t];
    scan[t] = h;
    __syncthreads();
    for (int off = 1; off < 256; off <<= 1) {
      int u = (t >= off) ? scan[t - off] : 0;
      __syncthreads();
      scan[t] += u;
      __syncthreads();
    }
    excl[t] = scan[t] - h;
    lcur[t] = scan[t] - h;
    gbase[t] = (t < NBUCK && h > 0) ? (t * SLOT + atomicAdd(&bcur[t], h)) : 0;
    __syncthreads();
    for (int i = t; i < nval; i += 256) {
      int e = e0 + i;
      int d = dst[e];
      int p = atomicAdd(&lcur[d >> 8], 1);
      sorted[p] = ((unsigned)d << 16) | (unsigned)src[e];
    }
    __syncthreads();
    for (int i = t; i < nval; i += 256) {
      unsigned pk = sorted[i];
      int bb = pk >> 24;                  // == dst>>8
      T[gbase[bb] + (i - excl[bb])] = pk;
    }
    return;
  }
  const int b2 = b - NEB;
  if (b2 < CONVB) {                       // ---- convert: x -> HAcb ----
    int i = b2 * 256 + t;                 // one thread per 8 elems (octet)
    if (i < N * 128 / 8) {
      int n = i >> 4, o = i & 15;         // octet o covers cols o*8..o*8+7
      float4 a = ((const float4*)x)[i * 2];
      float4 c = ((const float4*)x)[i * 2 + 1];
      f16x8 v;
      v[0] = (_Float16)a.x; v[1] = (_Float16)a.y; v[2] = (_Float16)a.z; v[3] = (_Float16)a.w;
      v[4] = (_Float16)c.x; v[5] = (_Float16)c.y; v[6] = (_Float16)c.z; v[7] = (_Float16)c.w;
      *(f16x8*)(HAcb + ((size_t)(o >> 2) * N + n) * 32 + (o & 3) * 8) = v;
    }
  } else if (b2 < CONVB + 128) {          // wf0: [wl0|wr0], K=256
    wfrag_build((b2 - CONVB) * 256 + t, 8, wl0, wr0, wf0);
  } else if (b2 < CONVB + 256) {          // wf1: [wl1|wr1]
    wfrag_build((b2 - CONVB - 128) * 256 + t, 8, wl1, wr1, wf1);
  } else if (b2 < CONVB + 320) {          // wfZ: 64 blocks
    int idx = (b2 - CONVB - 256) * 256 + t;
    int j = idx & 7;
    int lane = (idx >> 3) & 63;
    int kb = (idx >> 9) & 3;
    int ct = idx >> 11;                   // 0..7
    int c = ct * 16 + (lane & 15);
    int k = kb * 32 + (lane >> 4) * 8 + j;
    float v = (c < 64) ? wl2[c * 128 + k] : wr2[(c - 64) * 128 + k];
    wfZ[idx] = (_Float16)v;
  } else {                                // ---- mask branch ----
    int mb = b2 - (CONVB + 320);
    const float* Us = (mb < MASKB) ? u1 : u2;
    unsigned* MKs = (mb < MASKB) ? mk1 : mk2;
    int bb = (mb < MASKB) ? mb : (mb - MASKB);
#pragma unroll
    for (int k = 0; k < 8; ++k) {
      int i = (bb * 8 + k) * 256 + t;
      unsigned long long m = __ballot(Us[i] >= 0.3f);
      int lt = t & 63;
      if (lt == 0) MKs[i >> 5] = (unsigned)m;
      else if (lt == 32) MKs[i >> 5] = (unsigned)(m >> 32);
    }
  }
}

// Phase B: one block per bucket; offsets/degrees with 8-ALIGNED segments.
__global__ __launch_bounds__(256) void bucket_place_kernel(
    const unsigned* __restrict__ T, const int* __restrict__ bcur,
    int* __restrict__ offs, int* __restrict__ deg,
    unsigned short* __restrict__ elist) {
  __shared__ int dcnt[256], s[256], ncur[256];
  const int t = threadIdx.x;
  const int b = blockIdx.x;
  const int lo = b * SLOT;
  const int hi = lo + bcur[b];
  dcnt[t] = 0;
  __syncthreads();
  for (int i = lo + t; i < hi; i += 256) atomicAdd(&dcnt[(T[i] >> 16) & 255], 1);
  __syncthreads();
  const int v = dcnt[t];
  const int pv = (v + 7) & ~7;            // 8-aligned segment length
  s[t] = pv;
  __syncthreads();
  for (int off = 1; off < 256; off <<= 1) {
    int u = (t >= off) ? s[t - off] : 0;
    __syncthreads();
    s[t] += u;
    __syncthreads();
  }
  const int base = lo + s[t] - pv;
  const int node = b * 256 + t;
  if (node < N) { offs[node] = base; deg[node] = v; }
  ncur[t] = base;
  __syncthreads();
  for (int i = lo + t; i < hi; i += 256) {
    unsigned pk = T[i];
    int pos = atomicAdd(&ncur[(pk >> 16) & 255], 1);
    elist[pos] = (unsigned short)(pk & 0xffffu);
  }
}

// ---------------- gatherM v2: col-sliced L2-resident gather-mean -----------
// slice = bid&3 (XCD pairs {s,s+4} cache 3.2MB slice). Half-wave per node:
// 4 edge slots (g=ll>>3) x 8 lanes x f16x4 (8B) = 64B/edge-slice; 16-edge
// batch = 4 row + 4 scalar idx loads in flight; shfl_xor(8,16) reduce.
__global__ __launch_bounds__(256, 8) void gatherM_kernel(
    const _Float16* __restrict__ Hcb, const int* __restrict__ offs,
    const int* __restrict__ deg, const unsigned short* __restrict__ elist,
    _Float16* __restrict__ Mcb) {
  const int s = blockIdx.x & 3;
  const int nb = blockIdx.x >> 2;
  const _Float16* Hs = Hcb + (size_t)s * N * 32;
  _Float16* Ms = Mcb + (size_t)s * N * 32;
  const int t = threadIdx.x;
  const int hw = t >> 5;                  // half-wave 0..7
  const int ll = t & 31;
  const int g = ll >> 3;                  // edge slot 0..3
  const int cl = ll & 7;                  // cols 4*cl..4*cl+3
#pragma unroll 1
  for (int i = 0; i < 8; ++i) {
    int node = nb * 64 + hw * 8 + i;
    if (node >= N) break;
    const int e0 = offs[node];            // e0 % 8 == 0
    const int d = deg[node];
    const int e1 = e0 + d;
    float a0 = 0.f, a1 = 0.f, a2 = 0.f, a3 = 0.f;
    int e = e0;
    for (; e + 16 <= e1; e += 16) {
      int i0 = elist[e + g];
      int i1 = elist[e + g + 4];
      int i2 = elist[e + g + 8];
      int i3 = elist[e + g + 12];
      f16x4 v0 = *(const f16x4*)(Hs + (size_t)i0 * 32 + cl * 4);
      f16x4 v1 = *(const f16x4*)(Hs + (size_t)i1 * 32 + cl * 4);
      f16x4 v2 = *(const f16x4*)(Hs + (size_t)i2 * 32 + cl * 4);
      f16x4 v3 = *(const f16x4*)(Hs + (size_t)i3 * 32 + cl * 4);
      a0 += (float)v0[0] + (float)v1[0] + (float)v2[0] + (float)v3[0];
      a1 += (float)v0[1] + (float)v1[1] + (float)v2[1] + (float)v3[1];
      a2 += (float)v0[2] + (float)v1[2] + (float)v2[2] + (float)v3[2];
      a3 += (float)v0[3] + (float)v1[3] + (float)v2[3] + (float)v3[3];
    }
    for (; e + 4 <= e1; e += 4) {
      int i0 = elist[e + g];
      f16x4 v0 = *(const f16x4*)(Hs + (size_t)i0 * 32 + cl * 4);
      a0 += (float)v0[0]; a1 += (float)v0[1];
      a2 += (float)v0[2]; a3 += (float)v0[3];
    }
    if (e + g < e1) {                     // tail 1..3 edges: slots g < rem
      f16x4 v0 = *(const f16x4*)(Hs + (size_t)elist[e + g] * 32 + cl * 4);
      a0 += (float)v0[0]; a1 += (float)v0[1];
      a2 += (float)v0[2]; a3 += (float)v0[3];
    }
    a0 += __shfl_xor(a0, 8); a0 += __shfl_xor(a0, 16);
    a1 += __shfl_xor(a1, 8); a1 += __shfl_xor(a1, 16);
    a2 += __shfl_xor(a2, 8); a2 += __shfl_xor(a2, 16);
    a3 += __shfl_xor(a3, 8); a3 += __shfl_xor(a3, 16);
    if (g == 0) {
      float inv = 1.0f / (float)max(d, 1);
      f16x4 o;
      o[0] = (_Float16)(a0 * inv); o[1] = (_Float16)(a1 * inv);
      o[2] = (_Float16)(a2 * inv); o[3] = (_Float16)(a3 * inv);
      *(f16x4*)(Ms + (size_t)node * 32 + cl * 4) = o;
    }
  }
}

// ---------------- gemm128: A=[Mcb|Hcb] (K=256) -> relu/dropout -> outcb ----
__global__ __launch_bounds__(256, 8) void gemm128_kernel(
    const _Float16* __restrict__ Hcb, const _Float16* __restrict__ Mcb,
    const _Float16* __restrict__ Wf, const float* __restrict__ bias,
    const unsigned* __restrict__ MK, _Float16* __restrict__ outcb) {
  __shared__ __align__(16) _Float16 Af[8][64][8];      // 8 KB
  const int t = threadIdx.x;
  const int rowbase = blockIdx.x * 16;
  {
    int r = t >> 4, o = t & 15;
    size_t base = ((size_t)(o >> 2) * N + rowbase + r) * 32 + (o & 3) * 8;
    *(f16x8*)&Af[4 + (o >> 2)][(o & 3) * 16 + r][0] = *(const f16x8*)(Hcb + base);
    *(f16x8*)&Af[o >> 2][(o & 3) * 16 + r][0] = *(const f16x8*)(Mcb + base);
  }
  __syncthreads();

  const int lane = t & 63;
  const int w = t >> 6;
  const int n16 = lane & 15;
  const int qq = lane >> 4;
  const int colbase = w * 32;

  f32x4 acc[2];
  acc[0] = (f32x4){0.f, 0.f, 0.f, 0.f};
  acc[1] = (f32x4){0.f, 0.f, 0.f, 0.f};
#pragma unroll
  for (int kb = 0; kb < 8; ++kb) {
    f16x8 a = *(const f16x8*)&Af[kb][lane][0];
#pragma unroll
    for (int ct = 0; ct < 2; ++ct) {
      const int ctg = w * 2 + ct;
      f16x8 b = *(const f16x8*)(Wf + ((size_t)(ctg * 8 + kb) * 64 + lane) * 8);
      acc[ct] = __builtin_amdgcn_mfma_f32_16x16x32_f16(a, b, acc[ct], 0, 0, 0);
    }
  }
  // C/D: col = lane&15, row = (lane>>4)*4 + reg. Store col-blocked.
#pragma unroll
  for (int r = 0; r < 4; ++r) {
    int row = rowbase + qq * 4 + r;
    unsigned mw = MK[(size_t)row * 4 + w];
#pragma unroll
    for (int ct = 0; ct < 2; ++ct) {
      const int col = colbase + ct * 16 + n16;
      float v = fmaxf(acc[ct][r] + bias[col], 0.f);
      v = ((mw >> (ct * 16 + n16)) & 1u) ? v * (1.0f / 0.7f) : 0.0f;
      outcb[((size_t)(col >> 5) * N + row) * 32 + (col & 31)] = (_Float16)v;
    }
  }
}

// ---------------- gemmZ: layer-1 GEMM + layer-2 GEMM (h1 in LDS only) ------
__global__ __launch_bounds__(256, 8) void gemmZ_kernel(
    const _Float16* __restrict__ Hcb, const _Float16* __restrict__ Mcb,
    const _Float16* __restrict__ Wf, const float* __restrict__ bias,
    const unsigned* __restrict__ MK, const _Float16* __restrict__ WfZ,
    const float* __restrict__ bl2, _Float16* __restrict__ Y2cb,
    float* __restrict__ F) {
  __shared__ __align__(16) _Float16 Af[8][64][8];      // 8 KB
  __shared__ __align__(16) _Float16 Zf[16][136];       // 4.25 KB
  const int t = threadIdx.x;
  const int rowbase = blockIdx.x * 16;
  {
    int r = t >> 4, o = t & 15;
    size_t base = ((size_t)(o >> 2) * N + rowbase + r) * 32 + (o & 3) * 8;
    *(f16x8*)&Af[4 + (o >> 2)][(o & 3) * 16 + r][0] = *(const f16x8*)(Hcb + base);
    *(f16x8*)&Af[o >> 2][(o & 3) * 16 + r][0] = *(const f16x8*)(Mcb + base);
  }
  __syncthreads();

  const int lane = t & 63;
  const int w = t >> 6;
  const int n16 = lane & 15;
  const int qq = lane >> 4;
  const int colbase = w * 32;

  f32x4 acc[2];
  acc[0] = (f32x4){0.f, 0.f, 0.f, 0.f};
  acc[1] = (f32x4){0.f, 0.f, 0.f, 0.f};
#pragma unroll
  for (int kb = 0; kb < 8; ++kb) {
    f16x8 a = *(const f16x8*)&Af[kb][lane][0];
#pragma unroll
    for (int ct = 0; ct < 2; ++ct) {
      const int ctg = w * 2 + ct;
      f16x8 b = *(const f16x8*)(Wf + ((size_t)(ctg * 8 + kb) * 64 + lane) * 8);
      acc[ct] = __builtin_amdgcn_mfma_f32_16x16x32_f16(a, b, acc[ct], 0, 0, 0);
    }
  }
  // h1 = dropout(relu(acc+bias)) -> Zf
#pragma unroll
  for (int r = 0; r < 4; ++r) {
    int row = qq * 4 + r;                 // local 0..15
    unsigned mw = MK[(size_t)(rowbase + row) * 4 + w];
#pragma unroll
    for (int ct = 0; ct < 2; ++ct) {
      const int col = colbase + ct * 16 + n16;
      float v = fmaxf(acc[ct][r] + bias[col], 0.f);
      v = ((mw >> (ct * 16 + n16)) & 1u) ? v * (1.0f / 0.7f) : 0.0f;
      Zf[row][col] = (_Float16)v;
    }
  }
  __syncthreads();

  // layer-2 GEMM: A = Zf rows (K=128), B = WfZ
  f32x4 az[2];
  az[0] = (f32x4){0.f, 0.f, 0.f, 0.f};
  az[1] = (f32x4){0.f, 0.f, 0.f, 0.f};
#pragma unroll
  for (int kb = 0; kb < 4; ++kb) {
    f16x8 a = *(const f16x8*)&Zf[n16][kb * 32 + qq * 8];
#pragma unroll
    for (int ct = 0; ct < 2; ++ct) {
      const int ctg = w * 2 + ct;
      f16x8 b = *(const f16x8*)(WfZ + ((size_t)(ctg * 4 + kb) * 64 + lane) * 8);
      az[ct] = __builtin_amdgcn_mfma_f32_16x16x32_f16(a, b, az[ct], 0, 0, 0);
    }
  }
#pragma unroll
  for (int ct = 0; ct < 2; ++ct) {
    const int col = colbase + ct * 16 + n16;   // 0..127
#pragma unroll
    for (int r = 0; r < 4; ++r) {
      int row = rowbase + qq * 4 + r;
      float v = az[ct][r];
      if (col < 64)
        Y2cb[((size_t)(col >> 5) * N + row) * 32 + (col & 31)] = (_Float16)v;
      else
        F[(size_t)row * 64 + (col - 64)] = v + bl2[col - 64];
    }
  }
}

// ---------------- gatherY v2: col-sliced final gather + add ----------------
// slice = bid&1. Same wide organization as gatherM; out = F + mean (f32).
__global__ __launch_bounds__(256, 8) void gatherY_kernel(
    const _Float16* __restrict__ Y2cb, const float* __restrict__ F,
    const int* __restrict__ offs, const int* __restrict__ deg,
    const unsigned short* __restrict__ elist, float* __restrict__ out) {
  const int s = blockIdx.x & 1;
  const int nb = blockIdx.x >> 1;
  const _Float16* Ys = Y2cb + (size_t)s * N * 32;
  const int t = threadIdx.x;
  const int hw = t >> 5;
  const int ll = t & 31;
  const int g = ll >> 3;                  // edge slot 0..3
  const int cl = ll & 7;                  // cols 4*cl..4*cl+3
#pragma unroll 1
  for (int i = 0; i < 8; ++i) {
    int node = nb * 64 + hw * 8 + i;
    if (node >= N) break;
    const int e0 = offs[node];
    const int d = deg[node];
    const int e1 = e0 + d;
    float a0 = 0.f, a1 = 0.f, a2 = 0.f, a3 = 0.f;
    int e = e0;
    for (; e + 16 <= e1; e += 16) {
      int i0 = elist[e + g];
      int i1 = elist[e + g + 4];
      int i2 = elist[e + g + 8];
      int i3 = elist[e + g + 12];
      f16x4 v0 = *(const f16x4*)(Ys + (size_t)i0 * 32 + cl * 4);
      f16x4 v1 = *(const f16x4*)(Ys + (size_t)i1 * 32 + cl * 4);
      f16x4 v2 = *(const f16x4*)(Ys + (size_t)i2 * 32 + cl * 4);
      f16x4 v3 = *(const f16x4*)(Ys + (size_t)i3 * 32 + cl * 4);
      a0 += (float)v0[0] + (float)v1[0] + (float)v2[0] + (float)v3[0];
      a1 += (float)v0[1] + (float)v1[1] + (float)v2[1] + (float)v3[1];
      a2 += (float)v0[2] + (float)v1[2] + (float)v2[2] + (float)v3[2];
      a3 += (float)v0[3] + (float)v1[3] + (float)v2[3] + (float)v3[3];
    }
    for (; e + 4 <= e1; e += 4) {
      int i0 = elist[e + g];
      f16x4 v0 = *(const f16x4*)(Ys + (size_t)i0 * 32 + cl * 4);
      a0 += (float)v0[0]; a1 += (float)v0[1];
      a2 += (float)v0[2]; a3 += (float)v0[3];
    }
    if (e + g < e1) {                     // tail 1..3 edges
      f16x4 v0 = *(const f16x4*)(Ys + (size_t)elist[e + g] * 32 + cl * 4);
      a0 += (float)v0[0]; a1 += (float)v0[1];
      a2 += (float)v0[2]; a3 += (float)v0[3];
    }
    a0 += __shfl_xor(a0, 8); a0 += __shfl_xor(a0, 16);
    a1 += __shfl_xor(a1, 8); a1 += __shfl_xor(a1, 16);
    a2 += __shfl_xor(a2, 8); a2 += __shfl_xor(a2, 16);
    a3 += __shfl_xor(a3, 8); a3 += __shfl_xor(a3, 16);
    if (g == 0) {
      float inv = 1.0f / (float)max(d, 1);
      const float* fp = F + (size_t)node * 64 + s * 32 + cl * 4;
      float4 f = *(const float4*)fp;
      float4 o;
      o.x = f.x + a0 * inv;
      o.y = f.y + a1 * inv;
      o.z = f.z + a2 * inv;
      o.w = f.w + a3 * inv;
      *(float4*)(out + (size_t)node * 64 + s * 32 + cl * 4) = o;
    }
  }
}

extern "C" void kernel_launch(void* const* d_in, const int* in_sizes, int n_in,
                              void* d_out, int out_size, void* d_ws, size_t ws_size,
                              hipStream_t stream) {
  const float* x   = (const float*)d_in[0];
  const float* u1  = (const float*)d_in[1];
  const float* u2  = (const float*)d_in[2];
  const float* wl0 = (const float*)d_in[3];
  const float* bl0 = (const float*)d_in[4];
  const float* wr0 = (const float*)d_in[5];
  const float* wl1 = (const float*)d_in[6];
  const float* bl1 = (const float*)d_in[7];
  const float* wr1 = (const float*)d_in[8];
  const float* wl2 = (const float*)d_in[9];
  const float* bl2 = (const float*)d_in[10];
  const float* wr2 = (const float*)d_in[11];
  const int* edge  = (const int*)d_in[12];
  const int* src = edge;
  const int* dst = edge + E;

  // workspace layout (col-blocked H/M/Y2)
  _Float16* HAcb = (_Float16*)d_ws;                // [4][N][32] = N*128 f16
  _Float16* HBcb = HAcb + (size_t)N * 128;         // [4][N][32]
  _Float16* Y2cb = HBcb + (size_t)N * 128;         // [2][N][32] = N*64 f16
  float* F      = (float*)(Y2cb + (size_t)N * 64); // N x 64 f32
  int* offs     = (int*)(F + (size_t)N * 64);      // N
  int* deg      = offs + N;                        // N
  unsigned short* elist = (unsigned short*)(deg + N);  // NBUCK*SLOT u16
  uintptr_t pu = (uintptr_t)(elist + NBUCK * SLOT);
  pu = (pu + 15) & ~(uintptr_t)15;
  // union region: T (scatter staging, dead after place) / Mcb (after place)
  unsigned* T   = (unsigned*)pu;                   // NBUCK*SLOT u32 (4.9MB)
  _Float16* Mcb = (_Float16*)pu;                   // [4][N][32] (12.8MB)
  uintptr_t p2 = pu + (size_t)N * 128 * sizeof(_Float16);
  int* bcur     = (int*)p2;                        // NBUCK (counts)
  uintptr_t p = (uintptr_t)(bcur + NBUCK);
  p = (p + 15) & ~(uintptr_t)15;
  _Float16* wf0 = (_Float16*)p;                    // 8*8*512
  _Float16* wf1 = wf0 + 8 * 8 * 512;
  _Float16* wfZ = wf1 + 8 * 8 * 512;               // 8*4*512
  unsigned* mk1 = (unsigned*)(wfZ + 8 * 4 * 512);  // N*4 u32
  unsigned* mk2 = mk1 + (size_t)N * 4;             // N*4 u32

  // 0) bcur counts = 0
  hipMemsetAsync(bcur, 0, NBUCK * sizeof(int), stream);
  // 1) merged setup + scatter + masks
  setup_scatter_kernel<<<NEB + CONVB + 320 + 2 * MASKB, 256, 0, stream>>>(
      src, dst, bcur, T, x, u1, u2, wl0, wr0, wl1, wr1, wl2, wr2,
      HAcb, wf0, wf1, wfZ, mk1, mk2);
  // 2) place
  bucket_place_kernel<<<NBUCK, 256, 0, stream>>>(T, bcur, offs, deg, elist);

  // ---- Layer 0 ----
  gatherM_kernel<<<4 * GNB, 256, 0, stream>>>(HAcb, offs, deg, elist, Mcb);
  gemm128_kernel<<<N / 16, 256, 0, stream>>>(HAcb, Mcb, wf0, bl0, mk1, HBcb);
  // ---- Layer 1 (+ layer-2 GEMM fused) ----
  gatherM_kernel<<<4 * GNB, 256, 0, stream>>>(HBcb, offs, deg, elist, Mcb);
  gemmZ_kernel<<<N / 16, 256, 0, stream>>>(HBcb, Mcb, wf1, bl1, mk2, wfZ, bl2,
                                           Y2cb, F);
  // ---- Layer 2 gather + add ----
  gatherY_kernel<<<2 * GNB, 256, 0, stream>>>(Y2cb, F, offs, deg, elist,
                                              (float*)d_out);
}

// Round 13
// 279.644 us; speedup vs baseline: 1.2792x; 1.1959x over previous
//
#include <hip/hip_runtime.h>

// GraphSAGE 3-layer forward, MI355X. Round 22 (= R21 with compile fix):
//   R21 failed to compile: __builtin_nontemporal_* rejects HIP_vector_type
//   (float4/float2 structs). Fix: ext_vector_type float typedefs (f32x4v /
//   f32x2v) at the three offending sites. Theory unchanged from R21:
//   nt hints on all single-use streams protect L2 residency of gather-hot
//   arrays (H, Y2). Null result (<3%) => R17 structure is terminal.

constexpr int N = 50000;
constexpr int E = 800000;
constexpr int NBUCK = (N + 255) / 256;    // 196 dst-buckets (256 nodes each)
constexpr int CE = 4096;                  // edges per scatter chunk
constexpr int NEB = (E + CE - 1) / CE;    // 196
constexpr int SLOT = 6208;                // 4096 exp + sigma + 8-align pad
static_assert(N <= 65536, "u16 packing");
static_assert(N % 16 == 0, "16-row blocks need no bounds checks");

typedef _Float16 f16x8 __attribute__((ext_vector_type(8)));
typedef _Float16 f16x4 __attribute__((ext_vector_type(4)));
typedef _Float16 f16x2 __attribute__((ext_vector_type(2)));
typedef float f32x4 __attribute__((ext_vector_type(4)));
typedef float f32x4v __attribute__((ext_vector_type(4)));
typedef float f32x2v __attribute__((ext_vector_type(2)));
typedef unsigned short u16x8 __attribute__((ext_vector_type(8)));
typedef unsigned short u16x4 __attribute__((ext_vector_type(4)));

constexpr int CONVB = (N * 128 / 8 + 255) / 256;   // 3125 convert blocks
constexpr int MASKB = (N * 128) / (8 * 256);       // 3125 blocks per mask

// ---------------- merged setup + scatter + masks ---------------------------
// Wf[((ct*KB+kb)*64+lane)*8+j] = Wcat[ct*16+(lane&15)][kb*32+(lane>>4)*8+j]
__device__ inline void wfrag_build(int idx, int KB, const float* wl,
                                   const float* wr, _Float16* wf) {
  int j = idx & 7;
  int lane = (idx >> 3) & 63;
  int kb = (idx >> 9) % KB;
  int ct = (idx >> 9) / KB;
  int c = ct * 16 + (lane & 15);
  int k = kb * 32 + (lane >> 4) * 8 + j;
  float v = (k < 128) ? wl[c * 128 + k] : wr[c * 128 + (k - 128)];
  wf[idx] = (_Float16)v;
}

__global__ __launch_bounds__(256) void setup_scatter_kernel(
    const int* __restrict__ src, const int* __restrict__ dst,
    int* __restrict__ bcur, unsigned* __restrict__ T,
    const float* __restrict__ x,
    const float* __restrict__ u1, const float* __restrict__ u2,
    const float* __restrict__ wl0, const float* __restrict__ wr0,
    const float* __restrict__ wl1, const float* __restrict__ wr1,
    const float* __restrict__ wl2, const float* __restrict__ wr2,
    _Float16* __restrict__ HA, _Float16* __restrict__ wf0,
    _Float16* __restrict__ wf1, _Float16* __restrict__ wfZ,
    unsigned* __restrict__ mk1, unsigned* __restrict__ mk2) {
  __shared__ unsigned sorted[CE];
  __shared__ int hist[256], scan[256], excl[256], lcur[256], gbase[256];
  const int b = blockIdx.x;
  const int t = threadIdx.x;
  if (b < NEB) {                          // ---- scatter branch ----
    const int e0 = b * CE;
    const int nval = min(CE, E - e0);
    hist[t] = 0;
    __syncthreads();
    for (int i = t; i < nval; i += 256) atomicAdd(&hist[dst[e0 + i] >> 8], 1);
    __syncthreads();
    const int h = hist[t];
    scan[t] = h;
    __syncthreads();
    for (int off = 1; off < 256; off <<= 1) {
      int u = (t >= off) ? scan[t - off] : 0;
      __syncthreads();
      scan[t] += u;
      __syncthreads();
    }
    excl[t] = scan[t] - h;
    lcur[t] = scan[t] - h;
    gbase[t] = (t < NBUCK && h > 0) ? (t * SLOT + atomicAdd(&bcur[t], h)) : 0;
    __syncthreads();
    for (int i = t; i < nval; i += 256) {
      int e = e0 + i;
      int d = dst[e];
      int p = atomicAdd(&lcur[d >> 8], 1);
      sorted[p] = ((unsigned)d << 16) | (unsigned)src[e];
    }
    __syncthreads();
    for (int i = t; i < nval; i += 256) {
      unsigned pk = sorted[i];
      int bb = pk >> 24;                  // == dst>>8
      __builtin_nontemporal_store(pk, &T[gbase[bb] + (i - excl[bb])]);
    }
    return;
  }
  const int b2 = b - NEB;
  if (b2 < CONVB) {                       // ---- convert branch ----
    int i = b2 * 256 + t;                 // one thread per 8 elems
    if (i < N * 128 / 8) {
      f32x4v a = __builtin_nontemporal_load(&((const f32x4v*)x)[i * 2]);
      f32x4v c = __builtin_nontemporal_load(&((const f32x4v*)x)[i * 2 + 1]);
      f16x8 v;
      v[0] = (_Float16)a[0]; v[1] = (_Float16)a[1]; v[2] = (_Float16)a[2]; v[3] = (_Float16)a[3];
      v[4] = (_Float16)c[0]; v[5] = (_Float16)c[1]; v[6] = (_Float16)c[2]; v[7] = (_Float16)c[3];
      __builtin_nontemporal_store(v, &((f16x8*)HA)[i]);
    }
  } else if (b2 < CONVB + 128) {          // wf0: [wl0|wr0], K=256
    wfrag_build((b2 - CONVB) * 256 + t, 8, wl0, wr0, wf0);
  } else if (b2 < CONVB + 256) {          // wf1: [wl1|wr1]
    wfrag_build((b2 - CONVB - 128) * 256 + t, 8, wl1, wr1, wf1);
  } else if (b2 < CONVB + 320) {          // wfZ: 8ct*4kb*512 = 16384 = 64 blk
    int idx = (b2 - CONVB - 256) * 256 + t;
    int j = idx & 7;
    int lane = (idx >> 3) & 63;
    int kb = (idx >> 9) & 3;
    int ct = idx >> 11;                   // 0..7
    int c = ct * 16 + (lane & 15);
    int k = kb * 32 + (lane >> 4) * 8 + j;
    float v = (c < 64) ? wl2[c * 128 + k] : wr2[(c - 64) * 128 + k];
    wfZ[idx] = (_Float16)v;
  } else {                                // ---- mask branch ----
    int mb = b2 - (CONVB + 320);
    const float* Us = (mb < MASKB) ? u1 : u2;
    unsigned* MKs = (mb < MASKB) ? mk1 : mk2;
    int bb = (mb < MASKB) ? mb : (mb - MASKB);
#pragma unroll
    for (int k = 0; k < 8; ++k) {
      int i = (bb * 8 + k) * 256 + t;     // wave covers 64 consecutive elems
      float uv = __builtin_nontemporal_load(&Us[i]);
      unsigned long long m = __ballot(uv >= 0.3f);
      int lt = t & 63;
      if (lt == 0) __builtin_nontemporal_store((unsigned)m, &MKs[i >> 5]);
      else if (lt == 32) __builtin_nontemporal_store((unsigned)(m >> 32), &MKs[i >> 5]);
    }
  }
}

// Phase B: one block per bucket; offsets/degrees with 8-ALIGNED segments
// (u16 elist, ushort8 loads need e0%8==0), place edges as u16.
__global__ __launch_bounds__(256) void bucket_place_kernel(
    const unsigned* __restrict__ T, const int* __restrict__ bcur,
    int* __restrict__ offs, int* __restrict__ deg,
    unsigned short* __restrict__ elist) {
  __shared__ int dcnt[256], s[256], ncur[256];
  const int t = threadIdx.x;
  const int b = blockIdx.x;
  const int lo = b * SLOT;
  const int hi = lo + bcur[b];            // bcur holds per-bucket edge count
  dcnt[t] = 0;
  __syncthreads();
  for (int i = lo + t; i < hi; i += 256)
    atomicAdd(&dcnt[(__builtin_nontemporal_load(&T[i]) >> 16) & 255], 1);
  __syncthreads();
  const int v = dcnt[t];
  const int pv = (v + 7) & ~7;            // 8-aligned segment length
  s[t] = pv;
  __syncthreads();
  for (int off = 1; off < 256; off <<= 1) {
    int u = (t >= off) ? s[t - off] : 0;
    __syncthreads();
    s[t] += u;
    __syncthreads();
  }
  const int base = lo + s[t] - pv;        // within-bucket exclusive + slab base
  const int node = b * 256 + t;
  if (node < N) { offs[node] = base; deg[node] = v; }
  ncur[t] = base;
  __syncthreads();
  for (int i = lo + t; i < hi; i += 256) {
    unsigned pk = __builtin_nontemporal_load(&T[i]);
    int pos = atomicAdd(&ncur[(pk >> 16) & 255], 1);
    elist[pos] = (unsigned short)(pk & 0xffffu);
  }
}

// ---------------- fused layer 0: gather-mean -> LDS frags -> MFMA GEMM ----
__global__ __launch_bounds__(256, 8) void fused_layer_kernel(
    const _Float16* __restrict__ H, const int* __restrict__ offs,
    const int* __restrict__ deg, const unsigned short* __restrict__ elist,
    const _Float16* __restrict__ Wf, const float* __restrict__ bias,
    const unsigned* __restrict__ MK, _Float16* __restrict__ outp) {
  __shared__ __align__(16) _Float16 Af[8][64][8];      // [kb][lane][j] 8 KB
  const int t = threadIdx.x;
  const int rowbase = blockIdx.x * 16;

  // phase 1a: own H rows -> Af[4..7]
  {
    int r = t >> 4, o = t & 15;           // r: 0..15 row, o: 0..15 octet
    f16x8 v = *(const f16x8*)(H + (size_t)(rowbase + r) * 128 + o * 8);
    *(f16x8*)&Af[4 + (o >> 2)][(o & 3) * 16 + r][0] = v;
  }

  // phase 1b: gather-mean -> Af[0..3]; half-wave (32 lanes) per node
  {
    const int hw = t >> 5;                // 0..7
    const int ll = t & 31;                // cols 4*ll .. 4*ll+3
    const int kb = ll >> 3, q = (ll >> 1) & 3, j = (ll & 1) * 4;
#pragma unroll 1
    for (int i = 0; i < 2; ++i) {
      int r = hw * 2 + i;
      int node = rowbase + r;
      float a0 = 0.f, a1 = 0.f, a2 = 0.f, a3 = 0.f;
      const int e0 = offs[node];          // e0 % 8 == 0 (padded scan)
      const int d = deg[node];
      const int e1 = e0 + d;
      int e = e0;
      for (; e + 16 <= e1; e += 16) {
        u16x8 q0 = *(const u16x8*)(elist + e);
        u16x8 q1 = *(const u16x8*)(elist + e + 8);
        int s[16] = {q0[0], q0[1], q0[2], q0[3], q0[4], q0[5], q0[6], q0[7],
                     q1[0], q1[1], q1[2], q1[3], q1[4], q1[5], q1[6], q1[7]};
        f16x4 v[16];
#pragma unroll
        for (int u = 0; u < 16; ++u)
          v[u] = *(const f16x4*)(H + (size_t)s[u] * 128 + ll * 4);
#pragma unroll
        for (int u = 0; u < 16; ++u) {
          a0 += (float)v[u][0]; a1 += (float)v[u][1];
          a2 += (float)v[u][2]; a3 += (float)v[u][3];
        }
      }
      for (; e + 4 <= e1; e += 4) {
        u16x4 q4 = *(const u16x4*)(elist + e);
        int s[4] = {q4[0], q4[1], q4[2], q4[3]};
        f16x4 v[4];
#pragma unroll
        for (int u = 0; u < 4; ++u)
          v[u] = *(const f16x4*)(H + (size_t)s[u] * 128 + ll * 4);
#pragma unroll
        for (int u = 0; u < 4; ++u) {
          a0 += (float)v[u][0]; a1 += (float)v[u][1];
          a2 += (float)v[u][2]; a3 += (float)v[u][3];
        }
      }
      for (; e < e1; ++e) {
        f16x4 v = *(const f16x4*)(H + (size_t)elist[e] * 128 + ll * 4);
        a0 += (float)v[0]; a1 += (float)v[1];
        a2 += (float)v[2]; a3 += (float)v[3];
      }
      float inv = 1.0f / (float)max(d, 1);
      f16x4 o;
      o[0] = (_Float16)(a0 * inv); o[1] = (_Float16)(a1 * inv);
      o[2] = (_Float16)(a2 * inv); o[3] = (_Float16)(a3 * inv);
      *(f16x4*)&Af[kb][q * 16 + r][j] = o;
    }
  }
  __syncthreads();

  // phase 2: GEMM. Wave w covers cols w*32..w*32+31; 16 rows.
  const int lane = t & 63;
  const int w = t >> 6;
  const int n16 = lane & 15;
  const int qq = lane >> 4;
  const int colbase = w * 32;

  f32x4 acc[2];
  acc[0] = (f32x4){0.f, 0.f, 0.f, 0.f};
  acc[1] = (f32x4){0.f, 0.f, 0.f, 0.f};

#pragma unroll
  for (int kb = 0; kb < 8; ++kb) {
    f16x8 a = *(const f16x8*)&Af[kb][lane][0];
#pragma unroll
    for (int ct = 0; ct < 2; ++ct) {
      const int ctg = w * 2 + ct;
      f16x8 b = *(const f16x8*)(Wf + ((size_t)(ctg * 8 + kb) * 64 + lane) * 8);
      acc[ct] = __builtin_amdgcn_mfma_f32_16x16x32_f16(a, b, acc[ct], 0, 0, 0);
    }
  }

  // C/D layout: col = lane&15, row = (lane>>4)*4 + reg
#pragma unroll
  for (int r = 0; r < 4; ++r) {
    int row = rowbase + qq * 4 + r;
    unsigned mw = MK[(size_t)row * 4 + w];
#pragma unroll
    for (int ct = 0; ct < 2; ++ct) {
      const int col = colbase + ct * 16 + n16;
      float v = fmaxf(acc[ct][r] + bias[col], 0.f);
      v = ((mw >> (ct * 16 + n16)) & 1u) ? v * (1.0f / 0.7f) : 0.0f;
      __builtin_nontemporal_store((_Float16)v, &outp[(size_t)row * 128 + col]);
    }
  }
}

// ---------------- fused layer 1 + layer-2 GEMM ----------------------------
// h1 never hits global: epilogue -> Zf LDS, sync, layer-2 GEMM vs wfZ
// -> Y2 (f16) + F (f32). nt stores: Y2/F never re-read in this kernel.
__global__ __launch_bounds__(256, 8) void fused_layerZ_kernel(
    const _Float16* __restrict__ H, const int* __restrict__ offs,
    const int* __restrict__ deg, const unsigned short* __restrict__ elist,
    const _Float16* __restrict__ Wf, const float* __restrict__ bias,
    const unsigned* __restrict__ MK, const _Float16* __restrict__ WfZ,
    const float* __restrict__ bl2, _Float16* __restrict__ Y2,
    float* __restrict__ F) {
  __shared__ __align__(16) _Float16 Af[8][64][8];      // 8 KB
  __shared__ __align__(16) _Float16 Zf[16][136];       // 4.25 KB
  const int t = threadIdx.x;
  const int rowbase = blockIdx.x * 16;

  {
    int r = t >> 4, o = t & 15;
    f16x8 v = *(const f16x8*)(H + (size_t)(rowbase + r) * 128 + o * 8);
    *(f16x8*)&Af[4 + (o >> 2)][(o & 3) * 16 + r][0] = v;
  }

  {
    const int hw = t >> 5;
    const int ll = t & 31;
    const int kb = ll >> 3, q = (ll >> 1) & 3, j = (ll & 1) * 4;
#pragma unroll 1
    for (int i = 0; i < 2; ++i) {
      int r = hw * 2 + i;
      int node = rowbase + r;
      float a0 = 0.f, a1 = 0.f, a2 = 0.f, a3 = 0.f;
      const int e0 = offs[node];
      const int d = deg[node];
      const int e1 = e0 + d;
      int e = e0;
      for (; e + 16 <= e1; e += 16) {
        u16x8 q0 = *(const u16x8*)(elist + e);
        u16x8 q1 = *(const u16x8*)(elist + e + 8);
        int s[16] = {q0[0], q0[1], q0[2], q0[3], q0[4], q0[5], q0[6], q0[7],
                     q1[0], q1[1], q1[2], q1[3], q1[4], q1[5], q1[6], q1[7]};
        f16x4 v[16];
#pragma unroll
        for (int u = 0; u < 16; ++u)
          v[u] = *(const f16x4*)(H + (size_t)s[u] * 128 + ll * 4);
#pragma unroll
        for (int u = 0; u < 16; ++u) {
          a0 += (float)v[u][0]; a1 += (float)v[u][1];
          a2 += (float)v[u][2]; a3 += (float)v[u][3];
        }
      }
      for (; e + 4 <= e1; e += 4) {
        u16x4 q4 = *(const u16x4*)(elist + e);
        int s[4] = {q4[0], q4[1], q4[2], q4[3]};
        f16x4 v[4];
#pragma unroll
        for (int u = 0; u < 4; ++u)
          v[u] = *(const f16x4*)(H + (size_t)s[u] * 128 + ll * 4);
#pragma unroll
        for (int u = 0; u < 4; ++u) {
          a0 += (float)v[u][0]; a1 += (float)v[u][1];
          a2 += (float)v[u][2]; a3 += (float)v[u][3];
        }
      }
      for (; e < e1; ++e) {
        f16x4 v = *(const f16x4*)(H + (size_t)elist[e] * 128 + ll * 4);
        a0 += (float)v[0]; a1 += (float)v[1];
        a2 += (float)v[2]; a3 += (float)v[3];
      }
      float inv = 1.0f / (float)max(d, 1);
      f16x4 o;
      o[0] = (_Float16)(a0 * inv); o[1] = (_Float16)(a1 * inv);
      o[2] = (_Float16)(a2 * inv); o[3] = (_Float16)(a3 * inv);
      *(f16x4*)&Af[kb][q * 16 + r][j] = o;
    }
  }
  __syncthreads();

  const int lane = t & 63;
  const int w = t >> 6;
  const int n16 = lane & 15;
  const int qq = lane >> 4;
  const int colbase = w * 32;

  f32x4 acc[2];
  acc[0] = (f32x4){0.f, 0.f, 0.f, 0.f};
  acc[1] = (f32x4){0.f, 0.f, 0.f, 0.f};

#pragma unroll
  for (int kb = 0; kb < 8; ++kb) {
    f16x8 a = *(const f16x8*)&Af[kb][lane][0];
#pragma unroll
    for (int ct = 0; ct < 2; ++ct) {
      const int ctg = w * 2 + ct;
      f16x8 b = *(const f16x8*)(Wf + ((size_t)(ctg * 8 + kb) * 64 + lane) * 8);
      acc[ct] = __builtin_amdgcn_mfma_f32_16x16x32_f16(a, b, acc[ct], 0, 0, 0);
    }
  }

  // epilogue: h1 = dropout(relu(acc+bias)) -> Zf
#pragma unroll
  for (int r = 0; r < 4; ++r) {
    int row = qq * 4 + r;                 // local 0..15
    unsigned mw = MK[(size_t)(rowbase + row) * 4 + w];
#pragma unroll
    for (int ct = 0; ct < 2; ++ct) {
      const int col = colbase + ct * 16 + n16;
      float v = fmaxf(acc[ct][r] + bias[col], 0.f);
      v = ((mw >> (ct * 16 + n16)) & 1u) ? v * (1.0f / 0.7f) : 0.0f;
      Zf[row][col] = (_Float16)v;
    }
  }
  __syncthreads();

  // layer-2 GEMM: A = Zf rows (K=128), B = WfZ
  f32x4 az[2];
  az[0] = (f32x4){0.f, 0.f, 0.f, 0.f};
  az[1] = (f32x4){0.f, 0.f, 0.f, 0.f};
#pragma unroll
  for (int kb = 0; kb < 4; ++kb) {
    f16x8 a = *(const f16x8*)&Zf[n16][kb * 32 + qq * 8];
#pragma unroll
    for (int ct = 0; ct < 2; ++ct) {
      const int ctg = w * 2 + ct;
      f16x8 b = *(const f16x8*)(WfZ + ((size_t)(ctg * 4 + kb) * 64 + lane) * 8);
      az[ct] = __builtin_amdgcn_mfma_f32_16x16x32_f16(a, b, az[ct], 0, 0, 0);
    }
  }
#pragma unroll
  for (int ct = 0; ct < 2; ++ct) {
    const int col = colbase + ct * 16 + n16;   // 0..127
#pragma unroll
    for (int r = 0; r < 4; ++r) {
      int row = rowbase + qq * 4 + r;
      float v = az[ct][r];
      if (col < 64)
        __builtin_nontemporal_store((_Float16)v, &Y2[(size_t)row * 64 + col]);
      else
        __builtin_nontemporal_store(v + bl2[col - 64],
                                    &F[(size_t)row * 64 + (col - 64)]);
    }
  }
}

// ---------------- gather64 + final add: out = F + mean(Y2[nbrs]) ----------
__global__ __launch_bounds__(256) void gather64_add_kernel(
    const _Float16* __restrict__ Y2, const float* __restrict__ F,
    const int* __restrict__ offs, const int* __restrict__ deg,
    const unsigned short* __restrict__ elist, float* __restrict__ out) {
  int node = blockIdx.x * 8 + (threadIdx.x >> 5);
  if (node >= N) return;
  int l = threadIdx.x & 31;
  const int e0 = offs[node];              // e0 % 8 == 0
  const int d = deg[node];
  const int e1 = e0 + d;
  float a0 = 0.f, a1 = 0.f;
  int e = e0;
  for (; e + 16 <= e1; e += 16) {
    u16x8 q0 = *(const u16x8*)(elist + e);
    u16x8 q1 = *(const u16x8*)(elist + e + 8);
    int s[16] = {q0[0], q0[1], q0[2], q0[3], q0[4], q0[5], q0[6], q0[7],
                 q1[0], q1[1], q1[2], q1[3], q1[4], q1[5], q1[6], q1[7]};
    f16x2 v[16];
#pragma unroll
    for (int u = 0; u < 16; ++u)
      v[u] = *(const f16x2*)(Y2 + (size_t)s[u] * 64 + l * 2);
#pragma unroll
    for (int u = 0; u < 16; ++u) { a0 += (float)v[u][0]; a1 += (float)v[u][1]; }
  }
  for (; e + 4 <= e1; e += 4) {
    u16x4 q = *(const u16x4*)(elist + e);
    int s[4] = {q[0], q[1], q[2], q[3]};
    f16x2 v[4];
#pragma unroll
    for (int u = 0; u < 4; ++u)
      v[u] = *(const f16x2*)(Y2 + (size_t)s[u] * 64 + l * 2);
#pragma unroll
    for (int u = 0; u < 4; ++u) { a0 += (float)v[u][0]; a1 += (float)v[u][1]; }
  }
  for (; e < e1; ++e) {
    f16x2 v = *(const f16x2*)(Y2 + (size_t)elist[e] * 64 + l * 2);
    a0 += (float)v[0]; a1 += (float)v[1];
  }
  float inv = 1.0f / (float)max(d, 1);
  f32x2v f = __builtin_nontemporal_load(&((const f32x2v*)(F + (size_t)node * 64))[l]);
  f32x2v o;
  o[0] = f[0] + a0 * inv;
  o[1] = f[1] + a1 * inv;
  __builtin_nontemporal_store(o, &((f32x2v*)(out + (size_t)node * 64))[l]);
}

extern "C" void kernel_launch(void* const* d_in, const int* in_sizes, int n_in,
                              void* d_out, int out_size, void* d_ws, size_t ws_size,
                              hipStream_t stream) {
  const float* x   = (const float*)d_in[0];
  const float* u1  = (const float*)d_in[1];
  const float* u2  = (const float*)d_in[2];
  const float* wl0 = (const float*)d_in[3];
  const float* bl0 = (const float*)d_in[4];
  const float* wr0 = (const float*)d_in[5];
  const float* wl1 = (const float*)d_in[6];
  const float* bl1 = (const float*)d_in[7];
  const float* wr1 = (const float*)d_in[8];
  const float* wl2 = (const float*)d_in[9];
  const float* bl2 = (const float*)d_in[10];
  const float* wr2 = (const float*)d_in[11];
  const int* edge  = (const int*)d_in[12];
  const int* src = edge;
  const int* dst = edge + E;

  // workspace layout
  _Float16* HA  = (_Float16*)d_ws;                 // N x 128 f16
  _Float16* HB  = HA + (size_t)N * 128;            // N x 128 f16
  _Float16* Y2  = HB + (size_t)N * 128;            // N x 64 f16
  float* F      = (float*)(Y2 + (size_t)N * 64);   // N x 64 f32
  int* offs     = (int*)(F + (size_t)N * 64);      // N
  int* deg      = offs + N;                        // N
  unsigned short* elist = (unsigned short*)(deg + N);  // NBUCK*SLOT u16
  unsigned* T   = (unsigned*)(elist + NBUCK * SLOT);   // NBUCK*SLOT u32
  int* bcur     = (int*)(T + NBUCK * SLOT);        // NBUCK (counts)
  uintptr_t p = (uintptr_t)(bcur + NBUCK);
  p = (p + 15) & ~(uintptr_t)15;
  _Float16* wf0 = (_Float16*)p;                    // 8*8*512
  _Float16* wf1 = wf0 + 8 * 8 * 512;
  _Float16* wfZ = wf1 + 8 * 8 * 512;               // 8*4*512
  unsigned* mk1 = (unsigned*)(wfZ + 8 * 4 * 512);  // N*4 u32 (bit mask)
  unsigned* mk2 = mk1 + (size_t)N * 4;             // N*4 u32

  // 0) bcur counts = 0
  (void)hipMemsetAsync(bcur, 0, NBUCK * sizeof(int), stream);
  // 1) merged setup + scatter + masks
  setup_scatter_kernel<<<NEB + CONVB + 320 + 2 * MASKB, 256, 0, stream>>>(
      src, dst, bcur, T, x, u1, u2, wl0, wr0, wl1, wr1, wl2, wr2,
      HA, wf0, wf1, wfZ, mk1, mk2);
  // 2) place
  bucket_place_kernel<<<NBUCK, 256, 0, stream>>>(T, bcur, offs, deg, elist);

  const int GM16 = N / 16;             // 3125 fused-layer blocks
  const int GG64 = (N + 7) / 8;        // half-wave per node

  // ---- Layer 0 (fused gather+GEMM) ----
  fused_layer_kernel<<<GM16, 256, 0, stream>>>(HA, offs, deg, elist, wf0, bl0,
                                               mk1, HB);
  // ---- Layer 1 + Layer-2 GEMM (fused; h1 never hits global) ----
  fused_layerZ_kernel<<<GM16, 256, 0, stream>>>(HB, offs, deg, elist, wf1, bl1,
                                                mk2, wfZ, bl2, Y2, F);
  // ---- Layer 2 gather + add ----
  gather64_add_kernel<<<GG64, 256, 0, stream>>>(Y2, F, offs, deg, elist,
                                                (float*)d_out);
}

// Round 14
// 265.153 us; speedup vs baseline: 1.3491x; 1.0547x over previous
//
#include <hip/hip_runtime.h>

// GraphSAGE 3-layer forward, MI355X. Round 23 (= exact R17 revert, 265.5us):
//   R22 nt-hints REGRESSED (279.6us): nontemporal on scattered f16/f32
//   epilogue stores defeats L2 write-coalescing (WRITE 22.5->29.7MB).
//   Read-side pollution win never appeared (FETCH unchanged). Full lever
//   inventory now measured: MLP/widening/persistent/nt/f16-F all hurt;
//   fusion/occupancy/byte-cuts/CE all kept. R17 is the empirical optimum:
//   fused layers pinned at the random-gather fabric floor (~4.8 TB/s
//   effective row delivery), no pipe saturated, FETCH ~= mandatory.

constexpr int N = 50000;
constexpr int E = 800000;
constexpr int NBUCK = (N + 255) / 256;    // 196 dst-buckets (256 nodes each)
constexpr int CE = 4096;                  // edges per scatter chunk
constexpr int NEB = (E + CE - 1) / CE;    // 196
constexpr int SLOT = 6208;                // 4096 exp + sigma + 8-align pad
static_assert(N <= 65536, "u16 packing");
static_assert(N % 16 == 0, "16-row blocks need no bounds checks");

typedef _Float16 f16x8 __attribute__((ext_vector_type(8)));
typedef _Float16 f16x4 __attribute__((ext_vector_type(4)));
typedef _Float16 f16x2 __attribute__((ext_vector_type(2)));
typedef float f32x4 __attribute__((ext_vector_type(4)));
typedef unsigned short u16x8 __attribute__((ext_vector_type(8)));
typedef unsigned short u16x4 __attribute__((ext_vector_type(4)));

constexpr int CONVB = (N * 128 / 8 + 255) / 256;   // 3125 convert blocks
constexpr int MASKB = (N * 128) / (8 * 256);       // 3125 blocks per mask

// ---------------- merged setup + scatter + masks ---------------------------
// Wf[((ct*KB+kb)*64+lane)*8+j] = Wcat[ct*16+(lane&15)][kb*32+(lane>>4)*8+j]
__device__ inline void wfrag_build(int idx, int KB, const float* wl,
                                   const float* wr, _Float16* wf) {
  int j = idx & 7;
  int lane = (idx >> 3) & 63;
  int kb = (idx >> 9) % KB;
  int ct = (idx >> 9) / KB;
  int c = ct * 16 + (lane & 15);
  int k = kb * 32 + (lane >> 4) * 8 + j;
  float v = (k < 128) ? wl[c * 128 + k] : wr[c * 128 + (k - 128)];
  wf[idx] = (_Float16)v;
}

__global__ __launch_bounds__(256) void setup_scatter_kernel(
    const int* __restrict__ src, const int* __restrict__ dst,
    int* __restrict__ bcur, unsigned* __restrict__ T,
    const float* __restrict__ x,
    const float* __restrict__ u1, const float* __restrict__ u2,
    const float* __restrict__ wl0, const float* __restrict__ wr0,
    const float* __restrict__ wl1, const float* __restrict__ wr1,
    const float* __restrict__ wl2, const float* __restrict__ wr2,
    _Float16* __restrict__ HA, _Float16* __restrict__ wf0,
    _Float16* __restrict__ wf1, _Float16* __restrict__ wfZ,
    unsigned* __restrict__ mk1, unsigned* __restrict__ mk2) {
  __shared__ unsigned sorted[CE];
  __shared__ int hist[256], scan[256], excl[256], lcur[256], gbase[256];
  const int b = blockIdx.x;
  const int t = threadIdx.x;
  if (b < NEB) {                          // ---- scatter branch ----
    const int e0 = b * CE;
    const int nval = min(CE, E - e0);
    hist[t] = 0;
    __syncthreads();
    for (int i = t; i < nval; i += 256) atomicAdd(&hist[dst[e0 + i] >> 8], 1);
    __syncthreads();
    const int h = hist[t];
    scan[t] = h;
    __syncthreads();
    for (int off = 1; off < 256; off <<= 1) {
      int u = (t >= off) ? scan[t - off] : 0;
      __syncthreads();
      scan[t] += u;
      __syncthreads();
    }
    excl[t] = scan[t] - h;
    lcur[t] = scan[t] - h;
    gbase[t] = (t < NBUCK && h > 0) ? (t * SLOT + atomicAdd(&bcur[t], h)) : 0;
    __syncthreads();
    for (int i = t; i < nval; i += 256) {
      int e = e0 + i;
      int d = dst[e];
      int p = atomicAdd(&lcur[d >> 8], 1);
      sorted[p] = ((unsigned)d << 16) | (unsigned)src[e];
    }
    __syncthreads();
    for (int i = t; i < nval; i += 256) {
      unsigned pk = sorted[i];
      int bb = pk >> 24;                  // == dst>>8
      T[gbase[bb] + (i - excl[bb])] = pk;
    }
    return;
  }
  const int b2 = b - NEB;
  if (b2 < CONVB) {                       // ---- convert branch ----
    int i = b2 * 256 + t;                 // one thread per 8 elems
    if (i < N * 128 / 8) {
      float4 a = ((const float4*)x)[i * 2];
      float4 c = ((const float4*)x)[i * 2 + 1];
      f16x8 v;
      v[0] = (_Float16)a.x; v[1] = (_Float16)a.y; v[2] = (_Float16)a.z; v[3] = (_Float16)a.w;
      v[4] = (_Float16)c.x; v[5] = (_Float16)c.y; v[6] = (_Float16)c.z; v[7] = (_Float16)c.w;
      ((f16x8*)HA)[i] = v;
    }
  } else if (b2 < CONVB + 128) {          // wf0: [wl0|wr0], K=256
    wfrag_build((b2 - CONVB) * 256 + t, 8, wl0, wr0, wf0);
  } else if (b2 < CONVB + 256) {          // wf1: [wl1|wr1]
    wfrag_build((b2 - CONVB - 128) * 256 + t, 8, wl1, wr1, wf1);
  } else if (b2 < CONVB + 320) {          // wfZ: 8ct*4kb*512 = 16384 = 64 blk
    int idx = (b2 - CONVB - 256) * 256 + t;
    int j = idx & 7;
    int lane = (idx >> 3) & 63;
    int kb = (idx >> 9) & 3;
    int ct = idx >> 11;                   // 0..7
    int c = ct * 16 + (lane & 15);
    int k = kb * 32 + (lane >> 4) * 8 + j;
    float v = (c < 64) ? wl2[c * 128 + k] : wr2[(c - 64) * 128 + k];
    wfZ[idx] = (_Float16)v;
  } else {                                // ---- mask branch ----
    int mb = b2 - (CONVB + 320);
    const float* Us = (mb < MASKB) ? u1 : u2;
    unsigned* MKs = (mb < MASKB) ? mk1 : mk2;
    int bb = (mb < MASKB) ? mb : (mb - MASKB);
#pragma unroll
    for (int k = 0; k < 8; ++k) {
      int i = (bb * 8 + k) * 256 + t;     // wave covers 64 consecutive elems
      unsigned long long m = __ballot(Us[i] >= 0.3f);
      int lt = t & 63;
      if (lt == 0) MKs[i >> 5] = (unsigned)m;
      else if (lt == 32) MKs[i >> 5] = (unsigned)(m >> 32);
    }
  }
}

// Phase B: one block per bucket; offsets/degrees with 8-ALIGNED segments
// (u16 elist, ushort8 loads need e0%8==0), place edges as u16.
__global__ __launch_bounds__(256) void bucket_place_kernel(
    const unsigned* __restrict__ T, const int* __restrict__ bcur,
    int* __restrict__ offs, int* __restrict__ deg,
    unsigned short* __restrict__ elist) {
  __shared__ int dcnt[256], s[256], ncur[256];
  const int t = threadIdx.x;
  const int b = blockIdx.x;
  const int lo = b * SLOT;
  const int hi = lo + bcur[b];            // bcur holds per-bucket edge count
  dcnt[t] = 0;
  __syncthreads();
  for (int i = lo + t; i < hi; i += 256) atomicAdd(&dcnt[(T[i] >> 16) & 255], 1);
  __syncthreads();
  const int v = dcnt[t];
  const int pv = (v + 7) & ~7;            // 8-aligned segment length
  s[t] = pv;
  __syncthreads();
  for (int off = 1; off < 256; off <<= 1) {
    int u = (t >= off) ? s[t - off] : 0;
    __syncthreads();
    s[t] += u;
    __syncthreads();
  }
  const int base = lo + s[t] - pv;        // within-bucket exclusive + slab base
  const int node = b * 256 + t;
  if (node < N) { offs[node] = base; deg[node] = v; }
  ncur[t] = base;
  __syncthreads();
  for (int i = lo + t; i < hi; i += 256) {
    unsigned pk = T[i];
    int pos = atomicAdd(&ncur[(pk >> 16) & 255], 1);
    elist[pos] = (unsigned short)(pk & 0xffffu);
  }
}

// ---------------- fused layer 0: gather-mean -> LDS frags -> MFMA GEMM ----
__global__ __launch_bounds__(256, 8) void fused_layer_kernel(
    const _Float16* __restrict__ H, const int* __restrict__ offs,
    const int* __restrict__ deg, const unsigned short* __restrict__ elist,
    const _Float16* __restrict__ Wf, const float* __restrict__ bias,
    const unsigned* __restrict__ MK, _Float16* __restrict__ outp) {
  __shared__ __align__(16) _Float16 Af[8][64][8];      // [kb][lane][j] 8 KB
  const int t = threadIdx.x;
  const int rowbase = blockIdx.x * 16;

  // phase 1a: own H rows -> Af[4..7]
  {
    int r = t >> 4, o = t & 15;           // r: 0..15 row, o: 0..15 octet
    f16x8 v = *(const f16x8*)(H + (size_t)(rowbase + r) * 128 + o * 8);
    *(f16x8*)&Af[4 + (o >> 2)][(o & 3) * 16 + r][0] = v;
  }

  // phase 1b: gather-mean -> Af[0..3]; half-wave (32 lanes) per node
  {
    const int hw = t >> 5;                // 0..7
    const int ll = t & 31;                // cols 4*ll .. 4*ll+3
    const int kb = ll >> 3, q = (ll >> 1) & 3, j = (ll & 1) * 4;
#pragma unroll 1
    for (int i = 0; i < 2; ++i) {
      int r = hw * 2 + i;
      int node = rowbase + r;
      float a0 = 0.f, a1 = 0.f, a2 = 0.f, a3 = 0.f;
      const int e0 = offs[node];          // e0 % 8 == 0 (padded scan)
      const int d = deg[node];
      const int e1 = e0 + d;
      int e = e0;
      for (; e + 16 <= e1; e += 16) {
        u16x8 q0 = *(const u16x8*)(elist + e);
        u16x8 q1 = *(const u16x8*)(elist + e + 8);
        int s[16] = {q0[0], q0[1], q0[2], q0[3], q0[4], q0[5], q0[6], q0[7],
                     q1[0], q1[1], q1[2], q1[3], q1[4], q1[5], q1[6], q1[7]};
        f16x4 v[16];
#pragma unroll
        for (int u = 0; u < 16; ++u)
          v[u] = *(const f16x4*)(H + (size_t)s[u] * 128 + ll * 4);
#pragma unroll
        for (int u = 0; u < 16; ++u) {
          a0 += (float)v[u][0]; a1 += (float)v[u][1];
          a2 += (float)v[u][2]; a3 += (float)v[u][3];
        }
      }
      for (; e + 4 <= e1; e += 4) {
        u16x4 q4 = *(const u16x4*)(elist + e);
        int s[4] = {q4[0], q4[1], q4[2], q4[3]};
        f16x4 v[4];
#pragma unroll
        for (int u = 0; u < 4; ++u)
          v[u] = *(const f16x4*)(H + (size_t)s[u] * 128 + ll * 4);
#pragma unroll
        for (int u = 0; u < 4; ++u) {
          a0 += (float)v[u][0]; a1 += (float)v[u][1];
          a2 += (float)v[u][2]; a3 += (float)v[u][3];
        }
      }
      for (; e < e1; ++e) {
        f16x4 v = *(const f16x4*)(H + (size_t)elist[e] * 128 + ll * 4);
        a0 += (float)v[0]; a1 += (float)v[1];
        a2 += (float)v[2]; a3 += (float)v[3];
      }
      float inv = 1.0f / (float)max(d, 1);
      f16x4 o;
      o[0] = (_Float16)(a0 * inv); o[1] = (_Float16)(a1 * inv);
      o[2] = (_Float16)(a2 * inv); o[3] = (_Float16)(a3 * inv);
      *(f16x4*)&Af[kb][q * 16 + r][j] = o;
    }
  }
  __syncthreads();

  // phase 2: GEMM. Wave w covers cols w*32..w*32+31; 16 rows.
  const int lane = t & 63;
  const int w = t >> 6;
  const int n16 = lane & 15;
  const int qq = lane >> 4;
  const int colbase = w * 32;

  f32x4 acc[2];
  acc[0] = (f32x4){0.f, 0.f, 0.f, 0.f};
  acc[1] = (f32x4){0.f, 0.f, 0.f, 0.f};

#pragma unroll
  for (int kb = 0; kb < 8; ++kb) {
    f16x8 a = *(const f16x8*)&Af[kb][lane][0];
#pragma unroll
    for (int ct = 0; ct < 2; ++ct) {
      const int ctg = w * 2 + ct;
      f16x8 b = *(const f16x8*)(Wf + ((size_t)(ctg * 8 + kb) * 64 + lane) * 8);
      acc[ct] = __builtin_amdgcn_mfma_f32_16x16x32_f16(a, b, acc[ct], 0, 0, 0);
    }
  }

  // C/D layout: col = lane&15, row = (lane>>4)*4 + reg
#pragma unroll
  for (int r = 0; r < 4; ++r) {
    int row = rowbase + qq * 4 + r;
    unsigned mw = MK[(size_t)row * 4 + w];
#pragma unroll
    for (int ct = 0; ct < 2; ++ct) {
      const int col = colbase + ct * 16 + n16;
      float v = fmaxf(acc[ct][r] + bias[col], 0.f);
      v = ((mw >> (ct * 16 + n16)) & 1u) ? v * (1.0f / 0.7f) : 0.0f;
      outp[(size_t)row * 128 + col] = (_Float16)v;
    }
  }
}

// ---------------- fused layer 1 + layer-2 GEMM ----------------------------
// h1 never hits global: epilogue -> Zf LDS, sync, layer-2 GEMM vs wfZ
// -> Y2 (f16) + F (f32; 4B stores coalesce better than 2B, R16 lesson).
__global__ __launch_bounds__(256, 8) void fused_layerZ_kernel(
    const _Float16* __restrict__ H, const int* __restrict__ offs,
    const int* __restrict__ deg, const unsigned short* __restrict__ elist,
    const _Float16* __restrict__ Wf, const float* __restrict__ bias,
    const unsigned* __restrict__ MK, const _Float16* __restrict__ WfZ,
    const float* __restrict__ bl2, _Float16* __restrict__ Y2,
    float* __restrict__ F) {
  __shared__ __align__(16) _Float16 Af[8][64][8];      // 8 KB
  __shared__ __align__(16) _Float16 Zf[16][136];       // 4.25 KB
  const int t = threadIdx.x;
  const int rowbase = blockIdx.x * 16;

  {
    int r = t >> 4, o = t & 15;
    f16x8 v = *(const f16x8*)(H + (size_t)(rowbase + r) * 128 + o * 8);
    *(f16x8*)&Af[4 + (o >> 2)][(o & 3) * 16 + r][0] = v;
  }

  {
    const int hw = t >> 5;
    const int ll = t & 31;
    const int kb = ll >> 3, q = (ll >> 1) & 3, j = (ll & 1) * 4;
#pragma unroll 1
    for (int i = 0; i < 2; ++i) {
      int r = hw * 2 + i;
      int node = rowbase + r;
      float a0 = 0.f, a1 = 0.f, a2 = 0.f, a3 = 0.f;
      const int e0 = offs[node];
      const int d = deg[node];
      const int e1 = e0 + d;
      int e = e0;
      for (; e + 16 <= e1; e += 16) {
        u16x8 q0 = *(const u16x8*)(elist + e);
        u16x8 q1 = *(const u16x8*)(elist + e + 8);
        int s[16] = {q0[0], q0[1], q0[2], q0[3], q0[4], q0[5], q0[6], q0[7],
                     q1[0], q1[1], q1[2], q1[3], q1[4], q1[5], q1[6], q1[7]};
        f16x4 v[16];
#pragma unroll
        for (int u = 0; u < 16; ++u)
          v[u] = *(const f16x4*)(H + (size_t)s[u] * 128 + ll * 4);
#pragma unroll
        for (int u = 0; u < 16; ++u) {
          a0 += (float)v[u][0]; a1 += (float)v[u][1];
          a2 += (float)v[u][2]; a3 += (float)v[u][3];
        }
      }
      for (; e + 4 <= e1; e += 4) {
        u16x4 q4 = *(const u16x4*)(elist + e);
        int s[4] = {q4[0], q4[1], q4[2], q4[3]};
        f16x4 v[4];
#pragma unroll
        for (int u = 0; u < 4; ++u)
          v[u] = *(const f16x4*)(H + (size_t)s[u] * 128 + ll * 4);
#pragma unroll
        for (int u = 0; u < 4; ++u) {
          a0 += (float)v[u][0]; a1 += (float)v[u][1];
          a2 += (float)v[u][2]; a3 += (float)v[u][3];
        }
      }
      for (; e < e1; ++e) {
        f16x4 v = *(const f16x4*)(H + (size_t)elist[e] * 128 + ll * 4);
        a0 += (float)v[0]; a1 += (float)v[1];
        a2 += (float)v[2]; a3 += (float)v[3];
      }
      float inv = 1.0f / (float)max(d, 1);
      f16x4 o;
      o[0] = (_Float16)(a0 * inv); o[1] = (_Float16)(a1 * inv);
      o[2] = (_Float16)(a2 * inv); o[3] = (_Float16)(a3 * inv);
      *(f16x4*)&Af[kb][q * 16 + r][j] = o;
    }
  }
  __syncthreads();

  const int lane = t & 63;
  const int w = t >> 6;
  const int n16 = lane & 15;
  const int qq = lane >> 4;
  const int colbase = w * 32;

  f32x4 acc[2];
  acc[0] = (f32x4){0.f, 0.f, 0.f, 0.f};
  acc[1] = (f32x4){0.f, 0.f, 0.f, 0.f};

#pragma unroll
  for (int kb = 0; kb < 8; ++kb) {
    f16x8 a = *(const f16x8*)&Af[kb][lane][0];
#pragma unroll
    for (int ct = 0; ct < 2; ++ct) {
      const int ctg = w * 2 + ct;
      f16x8 b = *(const f16x8*)(Wf + ((size_t)(ctg * 8 + kb) * 64 + lane) * 8);
      acc[ct] = __builtin_amdgcn_mfma_f32_16x16x32_f16(a, b, acc[ct], 0, 0, 0);
    }
  }

  // epilogue: h1 = dropout(relu(acc+bias)) -> Zf
#pragma unroll
  for (int r = 0; r < 4; ++r) {
    int row = qq * 4 + r;                 // local 0..15
    unsigned mw = MK[(size_t)(rowbase + row) * 4 + w];
#pragma unroll
    for (int ct = 0; ct < 2; ++ct) {
      const int col = colbase + ct * 16 + n16;
      float v = fmaxf(acc[ct][r] + bias[col], 0.f);
      v = ((mw >> (ct * 16 + n16)) & 1u) ? v * (1.0f / 0.7f) : 0.0f;
      Zf[row][col] = (_Float16)v;
    }
  }
  __syncthreads();

  // layer-2 GEMM: A = Zf rows (K=128), B = WfZ
  f32x4 az[2];
  az[0] = (f32x4){0.f, 0.f, 0.f, 0.f};
  az[1] = (f32x4){0.f, 0.f, 0.f, 0.f};
#pragma unroll
  for (int kb = 0; kb < 4; ++kb) {
    f16x8 a = *(const f16x8*)&Zf[n16][kb * 32 + qq * 8];
#pragma unroll
    for (int ct = 0; ct < 2; ++ct) {
      const int ctg = w * 2 + ct;
      f16x8 b = *(const f16x8*)(WfZ + ((size_t)(ctg * 4 + kb) * 64 + lane) * 8);
      az[ct] = __builtin_amdgcn_mfma_f32_16x16x32_f16(a, b, az[ct], 0, 0, 0);
    }
  }
#pragma unroll
  for (int ct = 0; ct < 2; ++ct) {
    const int col = colbase + ct * 16 + n16;   // 0..127
#pragma unroll
    for (int r = 0; r < 4; ++r) {
      int row = rowbase + qq * 4 + r;
      float v = az[ct][r];
      if (col < 64) Y2[(size_t)row * 64 + col] = (_Float16)v;
      else F[(size_t)row * 64 + (col - 64)] = v + bl2[col - 64];
    }
  }
}

// ---------------- gather64 + final add: out = F + mean(Y2[nbrs]) ----------
__global__ __launch_bounds__(256) void gather64_add_kernel(
    const _Float16* __restrict__ Y2, const float* __restrict__ F,
    const int* __restrict__ offs, const int* __restrict__ deg,
    const unsigned short* __restrict__ elist, float* __restrict__ out) {
  int node = blockIdx.x * 8 + (threadIdx.x >> 5);
  if (node >= N) return;
  int l = threadIdx.x & 31;
  const int e0 = offs[node];              // e0 % 8 == 0
  const int d = deg[node];
  const int e1 = e0 + d;
  float a0 = 0.f, a1 = 0.f;
  int e = e0;
  for (; e + 16 <= e1; e += 16) {
    u16x8 q0 = *(const u16x8*)(elist + e);
    u16x8 q1 = *(const u16x8*)(elist + e + 8);
    int s[16] = {q0[0], q0[1], q0[2], q0[3], q0[4], q0[5], q0[6], q0[7],
                 q1[0], q1[1], q1[2], q1[3], q1[4], q1[5], q1[6], q1[7]};
    f16x2 v[16];
#pragma unroll
    for (int u = 0; u < 16; ++u)
      v[u] = *(const f16x2*)(Y2 + (size_t)s[u] * 64 + l * 2);
#pragma unroll
    for (int u = 0; u < 16; ++u) { a0 += (float)v[u][0]; a1 += (float)v[u][1]; }
  }
  for (; e + 4 <= e1; e += 4) {
    u16x4 q = *(const u16x4*)(elist + e);
    int s[4] = {q[0], q[1], q[2], q[3]};
    f16x2 v[4];
#pragma unroll
    for (int u = 0; u < 4; ++u)
      v[u] = *(const f16x2*)(Y2 + (size_t)s[u] * 64 + l * 2);
#pragma unroll
    for (int u = 0; u < 4; ++u) { a0 += (float)v[u][0]; a1 += (float)v[u][1]; }
  }
  for (; e < e1; ++e) {
    f16x2 v = *(const f16x2*)(Y2 + (size_t)elist[e] * 64 + l * 2);
    a0 += (float)v[0]; a1 += (float)v[1];
  }
  float inv = 1.0f / (float)max(d, 1);
  float2 f = ((const float2*)(F + (size_t)node * 64))[l];
  float2 o;
  o.x = f.x + a0 * inv;
  o.y = f.y + a1 * inv;
  ((float2*)(out + (size_t)node * 64))[l] = o;
}

extern "C" void kernel_launch(void* const* d_in, const int* in_sizes, int n_in,
                              void* d_out, int out_size, void* d_ws, size_t ws_size,
                              hipStream_t stream) {
  const float* x   = (const float*)d_in[0];
  const float* u1  = (const float*)d_in[1];
  const float* u2  = (const float*)d_in[2];
  const float* wl0 = (const float*)d_in[3];
  const float* bl0 = (const float*)d_in[4];
  const float* wr0 = (const float*)d_in[5];
  const float* wl1 = (const float*)d_in[6];
  const float* bl1 = (const float*)d_in[7];
  const float* wr1 = (const float*)d_in[8];
  const float* wl2 = (const float*)d_in[9];
  const float* bl2 = (const float*)d_in[10];
  const float* wr2 = (const float*)d_in[11];
  const int* edge  = (const int*)d_in[12];
  const int* src = edge;
  const int* dst = edge + E;

  // workspace layout
  _Float16* HA  = (_Float16*)d_ws;                 // N x 128 f16
  _Float16* HB  = HA + (size_t)N * 128;            // N x 128 f16
  _Float16* Y2  = HB + (size_t)N * 128;            // N x 64 f16
  float* F      = (float*)(Y2 + (size_t)N * 64);   // N x 64 f32
  int* offs     = (int*)(F + (size_t)N * 64);      // N
  int* deg      = offs + N;                        // N
  unsigned short* elist = (unsigned short*)(deg + N);  // NBUCK*SLOT u16
  unsigned* T   = (unsigned*)(elist + NBUCK * SLOT);   // NBUCK*SLOT u32
  int* bcur     = (int*)(T + NBUCK * SLOT);        // NBUCK (counts)
  uintptr_t p = (uintptr_t)(bcur + NBUCK);
  p = (p + 15) & ~(uintptr_t)15;
  _Float16* wf0 = (_Float16*)p;                    // 8*8*512
  _Float16* wf1 = wf0 + 8 * 8 * 512;
  _Float16* wfZ = wf1 + 8 * 8 * 512;               // 8*4*512
  unsigned* mk1 = (unsigned*)(wfZ + 8 * 4 * 512);  // N*4 u32 (bit mask)
  unsigned* mk2 = mk1 + (size_t)N * 4;             // N*4 u32

  // 0) bcur counts = 0
  (void)hipMemsetAsync(bcur, 0, NBUCK * sizeof(int), stream);
  // 1) merged setup + scatter + masks
  setup_scatter_kernel<<<NEB + CONVB + 320 + 2 * MASKB, 256, 0, stream>>>(
      src, dst, bcur, T, x, u1, u2, wl0, wr0, wl1, wr1, wl2, wr2,
      HA, wf0, wf1, wfZ, mk1, mk2);
  // 2) place
  bucket_place_kernel<<<NBUCK, 256, 0, stream>>>(T, bcur, offs, deg, elist);

  const int GM16 = N / 16;             // 3125 fused-layer blocks
  const int GG64 = (N + 7) / 8;        // half-wave per node

  // ---- Layer 0 (fused gather+GEMM) ----
  fused_layer_kernel<<<GM16, 256, 0, stream>>>(HA, offs, deg, elist, wf0, bl0,
                                               mk1, HB);
  // ---- Layer 1 + Layer-2 GEMM (fused; h1 never hits global) ----
  fused_layerZ_kernel<<<GM16, 256, 0, stream>>>(HB, offs, deg, elist, wf1, bl1,
                                                mk2, wfZ, bl2, Y2, F);
  // ---- Layer 2 gather + add ----
  gather64_add_kernel<<<GG64, 256, 0, stream>>>(Y2, F, offs, deg, elist,
                                                (float*)d_out);
}